// Round 2
// baseline (563.177 us; speedup 1.0000x reference)
//
#include <hip/hip_runtime.h>
#include <hip/hip_fp16.h>

typedef _Float16 f16;
typedef _Float16 f16x8 __attribute__((ext_vector_type(8)));
typedef float f32x4 __attribute__((ext_vector_type(4)));

#define NB 512
#define NL 16
#define NK 10000
#define KP 10016
#define NH 128

__device__ __forceinline__ float fast_exp2(float x) {
#if __has_builtin(__builtin_amdgcn_exp2f)
  return __builtin_amdgcn_exp2f(x);
#else
  return exp2f(x);
#endif
}
__device__ __forceinline__ float fast_rcp(float x) {
#if __has_builtin(__builtin_amdgcn_rcpf)
  return __builtin_amdgcn_rcpf(x);
#else
  return 1.f / x;
#endif
}
__device__ __forceinline__ float sigf(float x) {
  return fast_rcp(1.f + fast_exp2(-1.44269504f * x));
}
__device__ __forceinline__ float tanh_fast(float x) {
  return 2.f * fast_rcp(1.f + fast_exp2(-2.88539008f * x)) - 1.f;
}

// ---------------------------------------------------------------- prep ------
__global__ void prep_kernel(
    const float* __restrict__ x, const float* __restrict__ t0,
    const float* __restrict__ tau, const float* __restrict__ endi,
    const float* __restrict__ coords,
    const float* __restrict__ Wx1, const float* __restrict__ Wx2,
    const float* __restrict__ bx2, const float* __restrict__ Wres,
    const float* __restrict__ bres, const float* __restrict__ Wnode,
    const float* __restrict__ Wtau, const float* __restrict__ btau,
    const float* __restrict__ Wend1, const float* __restrict__ Wend2,
    const float* __restrict__ bend2, const float* __restrict__ Wcoord,
    const float* __restrict__ Wih, const float* __restrict__ Whh,
    const float* __restrict__ bih, const float* __restrict__ bhh,
    f16* __restrict__ xh, f16* __restrict__ t0h, f16* __restrict__ endh,
    f16* __restrict__ tauh, f16* __restrict__ coordh, f16* __restrict__ Wp,
    f16* __restrict__ Wih16, f16* __restrict__ Whh16, float* __restrict__ bsum) {
  const int tid0 = blockIdx.x * blockDim.x + threadIdx.x;
  const int stride = gridDim.x * blockDim.x;

  const int nWp = NH * KP;          // 1,282,048
  const int nW = 7 * 512 * NH;      // 458,752
  const int nb = 7 * 512;
  const int nxh = NB * NH;          // 65,536
  const int ntau = NB * NL * NH;    // 1,048,576
  const int nco = NB * 2 * NL * NH; // 2,097,152

  for (int i = tid0; i < nWp; i += stride) {
    const int h = i / KP, kk = i - h * KP;
    Wp[i] = (kk < NK) ? (f16)Wnode[h * NK + kk] : (f16)0.f;
  }
  for (int i = tid0; i < nW; i += stride) {
    Wih16[i] = (f16)Wih[i];
    Whh16[i] = (f16)Whh[i];
  }
  for (int i = tid0; i < nb; i += stride) bsum[i] = bih[i] + bhh[i];
  for (int i = tid0; i < nxh; i += stride) {
    const int b = i >> 7, h = i & 127;
    const float s = x[2 * b] * Wx1[0] + x[2 * b + 1] * Wx1[1];
    xh[i] = (f16)tanhf(s * Wx2[h] + bx2[h]);
    t0h[i] = (f16)tanhf(t0[b] * Wres[h] + bres[h]);
    const float e = endi[2 * b] * Wend1[0] + endi[2 * b + 1] * Wend1[1];
    endh[i] = (f16)(e * Wend2[h] + bend2[h]);
  }
  for (int i = tid0; i < ntau; i += stride) {
    const int h = i & 127, bl = i >> 7;
    tauh[i] = (f16)tanhf(tau[bl] * Wtau[h] + btau[h]);
  }
  for (int i = tid0; i < nco; i += stride) {
    const int h = i & 127, br = i >> 7;
    coordh[i] = (f16)(coords[2 * br] * Wcoord[2 * h] +
                      coords[2 * br + 1] * Wcoord[2 * h + 1]);
  }
}

// ------------------------------------------------------------ node GEMM -----
// C(16384x128) = A(16384x10000,f32) * Wp^T (Wp is [128][10016] f16, zero-padded)
__global__ __launch_bounds__(256) void node_gemm(const float* __restrict__ A,
                                                 const f16* __restrict__ Wp,
                                                 f16* __restrict__ Cn) {
  const int w = threadIdx.x >> 6;
  const int l = threadIdx.x & 63;
  const int lr = l & 15, kg = l >> 4;
  const int r0 = blockIdx.x * 64 + w * 16;
  const float* __restrict__ arow = A + (size_t)(r0 + lr) * NK + kg * 8;
  const f16* __restrict__ bbase = Wp + (size_t)lr * KP + kg * 8;

  f32x4 acc[8];
#pragma unroll
  for (int nt = 0; nt < 8; nt++) {
    f32x4 z = {0.f, 0.f, 0.f, 0.f};
    acc[nt] = z;
  }

  f32x4 A0 = __builtin_nontemporal_load((const f32x4*)(arow));
  f32x4 A1 = __builtin_nontemporal_load((const f32x4*)(arow + 4));
  f16x8 Bv[8];
#pragma unroll
  for (int nt = 0; nt < 8; nt++)
    Bv[nt] = *(const f16x8*)(bbase + (size_t)nt * 16 * KP);

  for (int s = 0; s < 313; s++) {
    const bool last = (s == 312);
    f32x4 P0 = {0.f, 0.f, 0.f, 0.f}, P1 = {0.f, 0.f, 0.f, 0.f};
    f16x8 Bn[8];
    if (!last) {
      const int kn = (s + 1) * 32;
      if ((s + 1 < 312) || (kg < 2)) {  // mask OOB A lanes on the K tail
        P0 = __builtin_nontemporal_load((const f32x4*)(arow + kn));
        P1 = __builtin_nontemporal_load((const f32x4*)(arow + kn + 4));
      }
#pragma unroll
      for (int nt = 0; nt < 8; nt++)
        Bn[nt] = *(const f16x8*)(bbase + (size_t)nt * 16 * KP + kn);
    }
    f16x8 av;
    av[0] = (f16)A0[0]; av[1] = (f16)A0[1]; av[2] = (f16)A0[2]; av[3] = (f16)A0[3];
    av[4] = (f16)A1[0]; av[5] = (f16)A1[1]; av[6] = (f16)A1[2]; av[7] = (f16)A1[3];
#pragma unroll
    for (int nt = 0; nt < 8; nt++)
      acc[nt] = __builtin_amdgcn_mfma_f32_16x16x32_f16(av, Bv[nt], acc[nt], 0, 0, 0);
    if (!last) {
      A0 = P0; A1 = P1;
#pragma unroll
      for (int nt = 0; nt < 8; nt++) Bv[nt] = Bn[nt];
    }
  }
  // C layout: row=(l>>4)*4+reg, col=l&15  (m89-verified)
  f16* crow = Cn + (size_t)(r0 + kg * 4) * NH + lr;
#pragma unroll
  for (int nt = 0; nt < 8; nt++)
#pragma unroll
    for (int jr = 0; jr < 4; jr++)
      crow[(size_t)jr * NH + nt * 16] = (f16)acc[nt][jr];
}

// --------------------------------------------------------------- LSTM -------
// grid: 7 k's x 32 batch-chunks of 16. One wg = 4 waves; wave w owns hidden
// units [w*32, w*32+32) across all four gates. Wih/Whh fragments in VGPRs.
__global__ __launch_bounds__(256, 1) void lstm_run(
    const f16* __restrict__ xh, const f16* __restrict__ t0h,
    const f16* __restrict__ endh, const f16* __restrict__ tauh,
    const f16* __restrict__ nodeh, const f16* __restrict__ coordh,
    const f16* __restrict__ Wih16, const f16* __restrict__ Whh16,
    const float* __restrict__ bsum, const float* __restrict__ hW1,
    const float* __restrict__ hb1, const float* __restrict__ hW2,
    const float* __restrict__ hb2, float* __restrict__ out) {
  __shared__ f16 hbuf[2][16 * NH];  // double-buffered h, XOR-swizzled bytes
  __shared__ float hu[16 * NH];

  const int k = blockIdx.x >> 5;
  const int b0 = (blockIdx.x & 31) << 4;
  const int w = threadIdx.x >> 6;
  const int l = threadIdx.x & 63;
  const int lr = l & 15, kg = l >> 4;

  // ---- load weight fragments into registers ----
  f16x8 Wh[4][8], Wi[4][8];
  float bias[8];
  {
    const f16* whb = Whh16 + (size_t)k * 512 * NH;
    const f16* wib = Wih16 + (size_t)k * 512 * NH;
#pragma unroll
    for (int tt = 0; tt < 8; tt++) {
      const int g = tt >> 1, nt = tt & 1;
      const int col = g * 128 + w * 32 + nt * 16 + lr;
      bias[tt] = bsum[k * 512 + col];
#pragma unroll
      for (int kc = 0; kc < 4; kc++) {
        Wh[kc][tt] = *(const f16x8*)(whb + (size_t)col * NH + kc * 32 + kg * 8);
        Wi[kc][tt] = *(const f16x8*)(wib + (size_t)col * NH + kc * 32 + kg * 8);
      }
    }
  }

  char* lds0 = (char*)&hbuf[0][0];
  // zero h buffer 0 (h0 = 0)
  {
    f32x4 z = {0.f, 0.f, 0.f, 0.f};
    *(f32x4*)(lds0 + threadIdx.x * 16) = z;
  }
  __syncthreads();

  float c[2][4] = {{0, 0, 0, 0}, {0, 0, 0, 0}};

  // precomputed swizzled LDS byte offsets (constant across t)
  int rdo[4];
#pragma unroll
  for (int kc = 0; kc < 4; kc++) {
    const int colb = (kc * 32 + kg * 8) * 2;
    rdo[kc] = lr * 256 + (colb ^ ((lr & 7) << 4));
  }
  int wro[2][4];
#pragma unroll
  for (int nt = 0; nt < 2; nt++)
#pragma unroll
    for (int jr = 0; jr < 4; jr++) {
      const int hrow = kg * 4 + jr;
      const int hcol = w * 32 + nt * 16 + lr;
      wro[nt][jr] = hrow * 256 + ((hcol * 2) ^ ((hrow & 7) << 4));
    }

  int len;
  switch (k) {
    case 0: len = 83; break;
    case 1: len = 19; break;
    case 2: len = 32; break;
    case 3: len = 32; break;
    case 4: len = 51; break;
    case 5: len = 64; break;
    default: len = 51; break;
  }

  int cur = 0;
  for (int t = 0; t < len; t++) {
    // ---- uniform component select ----
    const f16* cb; int bstr, idx;
    if (k == 2) { cb = nodeh; bstr = 32 * NH; idx = t; }
    else if (k == 3) { cb = coordh; bstr = 32 * NH; idx = t; }
    else if (k == 5) {
      const int q = t >> 2, r = t & 3;
      cb = (r == 0 || r == 2) ? nodeh : coordh;
      bstr = 32 * NH;
      idx = 2 * q + ((r >= 2) ? 1 : 0);
    } else {
      if (t == 0) { cb = xh; bstr = NH; idx = 0; }
      else if (t == 1) { cb = t0h; bstr = NH; idx = 0; }
      else if (t == len - 1) { cb = endh; bstr = NH; idx = 0; }
      else {
        const int u = t - 2;
        if (k == 0) {
          const int q = u / 5, r = u - 5 * q;
          if (r == 0) { cb = tauh; bstr = 16 * NH; idx = q; }
          else if (r == 1) { cb = nodeh; bstr = 32 * NH; idx = 2 * q; }
          else if (r == 2) { cb = coordh; bstr = 32 * NH; idx = 2 * q; }
          else if (r == 3) { cb = nodeh; bstr = 32 * NH; idx = 2 * q + 1; }
          else { cb = coordh; bstr = 32 * NH; idx = 2 * q + 1; }
        } else if (k == 1) { cb = tauh; bstr = 16 * NH; idx = u; }
        else if (k == 4) {
          const int q = u / 3, r = u - 3 * q;
          if (r == 0) { cb = tauh; bstr = 16 * NH; idx = q; }
          else { cb = nodeh; bstr = 32 * NH; idx = 2 * q + (r - 1); }
        } else {  // k == 6
          const int q = u / 3, r = u - 3 * q;
          if (r == 0) { cb = tauh; bstr = 16 * NH; idx = q; }
          else { cb = coordh; bstr = 32 * NH; idx = 2 * q + (r - 1); }
        }
      }
    }
    const f16* xp = cb + (size_t)(b0 + lr) * bstr + idx * NH + kg * 8;
    f16x8 ax[4];
#pragma unroll
    for (int kc = 0; kc < 4; kc++) ax[kc] = *(const f16x8*)(xp + kc * 32);

    char* rb = lds0 + cur * 4096;
    f16x8 ah[4];
#pragma unroll
    for (int kc = 0; kc < 4; kc++) ah[kc] = *(const f16x8*)(rb + rdo[kc]);

    f32x4 acc[8];
#pragma unroll
    for (int tt = 0; tt < 8; tt++) {
      f32x4 binit = {bias[tt], bias[tt], bias[tt], bias[tt]};
      acc[tt] = binit;
    }
#pragma unroll
    for (int kc = 0; kc < 4; kc++)
#pragma unroll
      for (int tt = 0; tt < 8; tt++)
        acc[tt] = __builtin_amdgcn_mfma_f32_16x16x32_f16(ah[kc], Wh[kc][tt], acc[tt], 0, 0, 0);
#pragma unroll
    for (int kc = 0; kc < 4; kc++)
#pragma unroll
      for (int tt = 0; tt < 8; tt++)
        acc[tt] = __builtin_amdgcn_mfma_f32_16x16x32_f16(ax[kc], Wi[kc][tt], acc[tt], 0, 0, 0);

    // gates: acc[g*2+nt], g = 0:i 1:f 2:g 3:o
    char* wb = lds0 + (cur ^ 1) * 4096;
#pragma unroll
    for (int nt = 0; nt < 2; nt++) {
#pragma unroll
      for (int jr = 0; jr < 4; jr++) {
        const float iv = acc[0 + nt][jr];
        const float fv = acc[2 + nt][jr];
        const float gv = acc[4 + nt][jr];
        const float ov = acc[6 + nt][jr];
        const float cn = sigf(fv) * c[nt][jr] + sigf(iv) * tanh_fast(gv);
        c[nt][jr] = cn;
        const float hn = sigf(ov) * tanh_fast(cn);
        *(f16*)(wb + wro[nt][jr]) = (f16)hn;
      }
    }
    __syncthreads();
    cur ^= 1;
  }

  // ---- head: out = tanh(h @ W1^T + b1) @ W2^T + b2 ----
  {
    char* rb = lds0 + cur * 4096;
    f16x8 ah[4];
#pragma unroll
    for (int kc = 0; kc < 4; kc++) ah[kc] = *(const f16x8*)(rb + rdo[kc]);
    const float* W1 = hW1 + (size_t)k * NH * NH;
    f32x4 hacc[2];
#pragma unroll
    for (int nt = 0; nt < 2; nt++) {
      const float b1 = hb1[k * NH + w * 32 + nt * 16 + lr];
      f32x4 binit = {b1, b1, b1, b1};
      hacc[nt] = binit;
    }
#pragma unroll
    for (int kc = 0; kc < 4; kc++) {
#pragma unroll
      for (int nt = 0; nt < 2; nt++) {
        const int col = w * 32 + nt * 16 + lr;
        const float* wrow = W1 + (size_t)col * NH + kc * 32 + kg * 8;
        const f32x4 w0 = *(const f32x4*)(wrow);
        const f32x4 w1 = *(const f32x4*)(wrow + 4);
        f16x8 wv;
        wv[0] = (f16)w0[0]; wv[1] = (f16)w0[1]; wv[2] = (f16)w0[2]; wv[3] = (f16)w0[3];
        wv[4] = (f16)w1[0]; wv[5] = (f16)w1[1]; wv[6] = (f16)w1[2]; wv[7] = (f16)w1[3];
        hacc[nt] = __builtin_amdgcn_mfma_f32_16x16x32_f16(ah[kc], wv, hacc[nt], 0, 0, 0);
      }
    }
#pragma unroll
    for (int nt = 0; nt < 2; nt++)
#pragma unroll
      for (int jr = 0; jr < 4; jr++)
        hu[(kg * 4 + jr) * NH + w * 32 + nt * 16 + lr] = tanh_fast(hacc[nt][jr]);
  }
  __syncthreads();
  if (w == 0) {
    const int b = l >> 2, part = l & 3;
    const float* W2 = hW2 + (size_t)k * NH;
    float s = 0.f;
#pragma unroll
    for (int j = 0; j < 32; j++)
      s += hu[b * NH + part * 32 + j] * W2[part * 32 + j];
    s += __shfl_xor(s, 1);
    s += __shfl_xor(s, 2);
    if (part == 0) out[k * NB + b0 + b] = s + hb2[k];
  }
}

// ------------------------------------------------------------- launch -------
extern "C" void kernel_launch(void* const* d_in, const int* in_sizes, int n_in,
                              void* d_out, int out_size, void* d_ws, size_t ws_size,
                              hipStream_t stream) {
  (void)in_sizes; (void)n_in; (void)out_size; (void)ws_size;
  const float* x = (const float*)d_in[0];
  const float* t0 = (const float*)d_in[1];
  const float* node = (const float*)d_in[2];
  const float* tau = (const float*)d_in[3];
  const float* endi = (const float*)d_in[4];
  const float* coords = (const float*)d_in[5];
  const float* Wx1 = (const float*)d_in[6];
  const float* Wx2 = (const float*)d_in[7];
  const float* bx2 = (const float*)d_in[8];
  const float* Wres = (const float*)d_in[9];
  const float* bres = (const float*)d_in[10];
  const float* Wnode = (const float*)d_in[11];
  const float* Wtau = (const float*)d_in[12];
  const float* btau = (const float*)d_in[13];
  const float* Wend1 = (const float*)d_in[14];
  const float* Wend2 = (const float*)d_in[15];
  const float* bend2 = (const float*)d_in[16];
  const float* Wcoord = (const float*)d_in[17];
  const float* Wih = (const float*)d_in[18];
  const float* Whh = (const float*)d_in[19];
  const float* bih = (const float*)d_in[20];
  const float* bhh = (const float*)d_in[21];
  const float* hW1 = (const float*)d_in[22];
  const float* hb1 = (const float*)d_in[23];
  const float* hW2 = (const float*)d_in[24];
  const float* hb2 = (const float*)d_in[25];

  char* ws = (char*)d_ws;
  f16* xh = (f16*)ws;      ws += (size_t)NB * NH * 2;
  f16* t0h = (f16*)ws;     ws += (size_t)NB * NH * 2;
  f16* endh = (f16*)ws;    ws += (size_t)NB * NH * 2;
  f16* tauh = (f16*)ws;    ws += (size_t)NB * NL * NH * 2;
  f16* nodeh = (f16*)ws;   ws += (size_t)NB * 2 * NL * NH * 2;
  f16* coordh = (f16*)ws;  ws += (size_t)NB * 2 * NL * NH * 2;
  f16* Wp = (f16*)ws;      ws += (size_t)NH * KP * 2;
  f16* Wih16 = (f16*)ws;   ws += (size_t)7 * 512 * NH * 2;
  f16* Whh16 = (f16*)ws;   ws += (size_t)7 * 512 * NH * 2;
  float* bsum = (float*)ws;

  prep_kernel<<<1024, 256, 0, stream>>>(
      x, t0, tau, endi, coords, Wx1, Wx2, bx2, Wres, bres, Wnode, Wtau, btau,
      Wend1, Wend2, bend2, Wcoord, Wih, Whh, bih, bhh,
      xh, t0h, endh, tauh, coordh, Wp, Wih16, Whh16, bsum);
  node_gemm<<<256, 256, 0, stream>>>(node, Wp, nodeh);
  lstm_run<<<224, 256, 0, stream>>>(xh, t0h, endh, tauh, nodeh, coordh,
                                    Wih16, Whh16, bsum, hW1, hb1, hW2, hb2,
                                    (float*)d_out);
}

// Round 3
// 435.063 us; speedup vs baseline: 1.2945x; 1.2945x over previous
//
#include <hip/hip_runtime.h>
#include <hip/hip_fp16.h>

typedef _Float16 f16;
typedef _Float16 f16x8 __attribute__((ext_vector_type(8)));
typedef float f32x4 __attribute__((ext_vector_type(4)));

#define NB 512
#define NL 16
#define NK 10000
#define NH 128
#define NSTEP 313  // ceil(10000/32), zero-padded K

__device__ __forceinline__ float fast_exp2(float x) {
#if __has_builtin(__builtin_amdgcn_exp2f)
  return __builtin_amdgcn_exp2f(x);
#else
  return exp2f(x);
#endif
}
__device__ __forceinline__ float fast_rcp(float x) {
#if __has_builtin(__builtin_amdgcn_rcpf)
  return __builtin_amdgcn_rcpf(x);
#else
  return 1.f / x;
#endif
}
__device__ __forceinline__ float sigf(float x) {
  return fast_rcp(1.f + fast_exp2(-1.44269504f * x));
}
__device__ __forceinline__ float tanh_fast(float x) {
  return 2.f * fast_rcp(1.f + fast_exp2(-2.88539008f * x)) - 1.f;
}

// ---------------------------------------------------------------- prep ------
// Wf: B in MFMA-fragment order: [s][nt][lane][e] with lane=(kg*16+lr),
// value = Wnode[col=nt*16+lr][k=s*32+kg*8+e], zero-padded past K=10000.
__global__ void prep_kernel(
    const float* __restrict__ x, const float* __restrict__ t0,
    const float* __restrict__ tau, const float* __restrict__ endi,
    const float* __restrict__ coords,
    const float* __restrict__ Wx1, const float* __restrict__ Wx2,
    const float* __restrict__ bx2, const float* __restrict__ Wres,
    const float* __restrict__ bres, const float* __restrict__ Wnode,
    const float* __restrict__ Wtau, const float* __restrict__ btau,
    const float* __restrict__ Wend1, const float* __restrict__ Wend2,
    const float* __restrict__ bend2, const float* __restrict__ Wcoord,
    const float* __restrict__ Wih, const float* __restrict__ Whh,
    const float* __restrict__ bih, const float* __restrict__ bhh,
    f16* __restrict__ xh, f16* __restrict__ t0h, f16* __restrict__ endh,
    f16* __restrict__ tauh, f16* __restrict__ coordh, f16* __restrict__ Wf,
    f16* __restrict__ Wih16, f16* __restrict__ Whh16, float* __restrict__ bsum) {
  const int tid0 = blockIdx.x * blockDim.x + threadIdx.x;
  const int stride = gridDim.x * blockDim.x;

  const int nWf = NSTEP * 4096;     // 1,282,048
  const int nW = 7 * 512 * NH;      // 458,752
  const int nb = 7 * 512;
  const int nxh = NB * NH;          // 65,536
  const int ntau = NB * NL * NH;    // 1,048,576
  const int nco = NB * 2 * NL * NH; // 2,097,152

  for (int i = tid0; i < nWf; i += stride) {
    const int s = i >> 12, r = i & 4095;
    const int nt = r >> 9, l2 = r & 511;
    const int lane = l2 >> 3, e = l2 & 7;
    const int kg = lane >> 4, lr = lane & 15;
    const int col = nt * 16 + lr;
    const int k = s * 32 + kg * 8 + e;
    Wf[i] = (k < NK) ? (f16)Wnode[(size_t)col * NK + k] : (f16)0.f;
  }
  for (int i = tid0; i < nW; i += stride) {
    Wih16[i] = (f16)Wih[i];
    Whh16[i] = (f16)Whh[i];
  }
  for (int i = tid0; i < nb; i += stride) bsum[i] = bih[i] + bhh[i];
  for (int i = tid0; i < nxh; i += stride) {
    const int b = i >> 7, h = i & 127;
    const float s = x[2 * b] * Wx1[0] + x[2 * b + 1] * Wx1[1];
    xh[i] = (f16)tanhf(s * Wx2[h] + bx2[h]);
    t0h[i] = (f16)tanhf(t0[b] * Wres[h] + bres[h]);
    const float e = endi[2 * b] * Wend1[0] + endi[2 * b + 1] * Wend1[1];
    endh[i] = (f16)(e * Wend2[h] + bend2[h]);
  }
  for (int i = tid0; i < ntau; i += stride) {
    const int h = i & 127, bl = i >> 7;
    tauh[i] = (f16)tanhf(tau[bl] * Wtau[h] + btau[h]);
  }
  for (int i = tid0; i < nco; i += stride) {
    const int h = i & 127, br = i >> 7;
    coordh[i] = (f16)(coords[2 * br] * Wcoord[2 * h] +
                      coords[2 * br + 1] * Wcoord[2 * h + 1]);
  }
}

// ------------------------------------------------------------ node GEMM -----
// C(16384x128) = A(16384x10000,f32) * W^T, W pre-arranged as fragments (Wf).
// 512 thr = 8 waves: wave = (kw<<2)|mw. mw picks 16-row subtile, kw splits K
// in halves (157/156 steps). No main-loop barriers; LDS reduce at epilogue.
__global__ __launch_bounds__(512) void node_gemm(const float* __restrict__ A,
                                                 const f16* __restrict__ Wf,
                                                 f16* __restrict__ Cn) {
  __shared__ float hred[4][16][132];
  const int w = threadIdx.x >> 6;
  const int l = threadIdx.x & 63;
  const int lr = l & 15, kg = l >> 4;
  const int mw = w & 3, kw = w >> 2;
  const int r0 = blockIdx.x * 64 + mw * 16;
  const int s0 = kw ? 157 : 0;
  const int ns = kw ? 156 : 157;
  const float* __restrict__ arow =
      A + (size_t)(r0 + lr) * NK + (size_t)s0 * 32 + kg * 8;
  const f16* __restrict__ bbase = Wf + (size_t)s0 * 4096 + l * 8;

  f32x4 acc[8];
#pragma unroll
  for (int nt = 0; nt < 8; nt++) {
    f32x4 z = {0.f, 0.f, 0.f, 0.f};
    acc[nt] = z;
  }

  f32x4 A0 = __builtin_nontemporal_load((const f32x4*)(arow));
  f32x4 A1 = __builtin_nontemporal_load((const f32x4*)(arow + 4));
  f16x8 Bv[8];
#pragma unroll
  for (int nt = 0; nt < 8; nt++) Bv[nt] = *(const f16x8*)(bbase + nt * 512);

  for (int s = 0; s < ns; s++) {
    const bool last = (s == ns - 1);
    f32x4 P0 = {0.f, 0.f, 0.f, 0.f}, P1 = {0.f, 0.f, 0.f, 0.f};
    f16x8 Bn[8];
    if (!last) {
      // mask A's K tail (global step 312 has k>=10000 for kg>=2)
      const bool ok = (kw == 0) || (s + 1 != 155) || (kg < 2);
      const float* an = arow + (size_t)(s + 1) * 32;
      if (ok) {
        P0 = __builtin_nontemporal_load((const f32x4*)(an));
        P1 = __builtin_nontemporal_load((const f32x4*)(an + 4));
      }
      const f16* bn = bbase + (size_t)(s + 1) * 4096;
#pragma unroll
      for (int nt = 0; nt < 8; nt++) Bn[nt] = *(const f16x8*)(bn + nt * 512);
    }
    f16x8 av;
    av[0] = (f16)A0[0]; av[1] = (f16)A0[1]; av[2] = (f16)A0[2]; av[3] = (f16)A0[3];
    av[4] = (f16)A1[0]; av[5] = (f16)A1[1]; av[6] = (f16)A1[2]; av[7] = (f16)A1[3];
#pragma unroll
    for (int nt = 0; nt < 8; nt++)
      acc[nt] = __builtin_amdgcn_mfma_f32_16x16x32_f16(av, Bv[nt], acc[nt], 0, 0, 0);
    if (!last) {
      A0 = P0; A1 = P1;
#pragma unroll
      for (int nt = 0; nt < 8; nt++) Bv[nt] = Bn[nt];
    }
  }

  // K-split reduce: kw=1 -> LDS, kw=0 adds and stores.
  if (kw == 1) {
#pragma unroll
    for (int nt = 0; nt < 8; nt++)
#pragma unroll
      for (int jr = 0; jr < 4; jr++)
        hred[mw][kg * 4 + jr][nt * 16 + lr] = acc[nt][jr];
  }
  __syncthreads();
  if (kw == 0) {
    f16* crow = Cn + (size_t)(r0 + kg * 4) * NH + lr;
#pragma unroll
    for (int nt = 0; nt < 8; nt++)
#pragma unroll
      for (int jr = 0; jr < 4; jr++) {
        const float v = acc[nt][jr] + hred[mw][kg * 4 + jr][nt * 16 + lr];
        crow[(size_t)jr * NH + nt * 16] = (f16)v;
      }
  }
}

// --------------------------------------------------------------- LSTM -------
// grid: 7 k's x 32 batch-chunks of 16. One wg = 4 waves; wave w owns hidden
// units [w*32, w*32+32) across all four gates. Wih/Whh fragments in VGPRs.
// x-fragments for step t+1 are prefetched into registers during step t.
__global__ __launch_bounds__(256, 1) void lstm_run(
    const f16* __restrict__ xh, const f16* __restrict__ t0h,
    const f16* __restrict__ endh, const f16* __restrict__ tauh,
    const f16* __restrict__ nodeh, const f16* __restrict__ coordh,
    const f16* __restrict__ Wih16, const f16* __restrict__ Whh16,
    const float* __restrict__ bsum, const float* __restrict__ hW1,
    const float* __restrict__ hb1, const float* __restrict__ hW2,
    const float* __restrict__ hb2, float* __restrict__ out) {
  __shared__ f16 hbuf[2][16 * NH];  // double-buffered h, XOR-swizzled bytes
  __shared__ float hu[16 * NH];

  const int k = blockIdx.x >> 5;
  const int b0 = (blockIdx.x & 31) << 4;
  const int w = threadIdx.x >> 6;
  const int l = threadIdx.x & 63;
  const int lr = l & 15, kg = l >> 4;

  int len;
  switch (k) {
    case 0: len = 83; break;
    case 1: len = 19; break;
    case 2: len = 32; break;
    case 3: len = 32; break;
    case 4: len = 51; break;
    case 5: len = 64; break;
    default: len = 51; break;
  }

  // per-step input fragment pointer (wave-uniform select logic)
  auto xptr = [&](int t) -> const f16* {
    const f16* cb; int bstr, idx;
    if (k == 2) { cb = nodeh; bstr = 32 * NH; idx = t; }
    else if (k == 3) { cb = coordh; bstr = 32 * NH; idx = t; }
    else if (k == 5) {
      const int q = t >> 2, r = t & 3;
      cb = (r == 0 || r == 2) ? nodeh : coordh;
      bstr = 32 * NH;
      idx = 2 * q + ((r >= 2) ? 1 : 0);
    } else {
      if (t == 0) { cb = xh; bstr = NH; idx = 0; }
      else if (t == 1) { cb = t0h; bstr = NH; idx = 0; }
      else if (t == len - 1) { cb = endh; bstr = NH; idx = 0; }
      else {
        const int u = t - 2;
        if (k == 0) {
          const int q = u / 5, r = u - 5 * q;
          if (r == 0) { cb = tauh; bstr = 16 * NH; idx = q; }
          else if (r == 1) { cb = nodeh; bstr = 32 * NH; idx = 2 * q; }
          else if (r == 2) { cb = coordh; bstr = 32 * NH; idx = 2 * q; }
          else if (r == 3) { cb = nodeh; bstr = 32 * NH; idx = 2 * q + 1; }
          else { cb = coordh; bstr = 32 * NH; idx = 2 * q + 1; }
        } else if (k == 1) { cb = tauh; bstr = 16 * NH; idx = u; }
        else if (k == 4) {
          const int q = u / 3, r = u - 3 * q;
          if (r == 0) { cb = tauh; bstr = 16 * NH; idx = q; }
          else { cb = nodeh; bstr = 32 * NH; idx = 2 * q + (r - 1); }
        } else {  // k == 6
          const int q = u / 3, r = u - 3 * q;
          if (r == 0) { cb = tauh; bstr = 16 * NH; idx = q; }
          else { cb = coordh; bstr = 32 * NH; idx = 2 * q + (r - 1); }
        }
      }
    }
    return cb + (size_t)(b0 + lr) * bstr + idx * NH + kg * 8;
  };

  // ---- load weight fragments into registers ----
  f16x8 Wh[4][8], Wi[4][8];
  float bias[8];
  {
    const f16* whb = Whh16 + (size_t)k * 512 * NH;
    const f16* wib = Wih16 + (size_t)k * 512 * NH;
#pragma unroll
    for (int tt = 0; tt < 8; tt++) {
      const int g = tt >> 1, nt = tt & 1;
      const int col = g * 128 + w * 32 + nt * 16 + lr;
      bias[tt] = bsum[k * 512 + col];
#pragma unroll
      for (int kc = 0; kc < 4; kc++) {
        Wh[kc][tt] = *(const f16x8*)(whb + (size_t)col * NH + kc * 32 + kg * 8);
        Wi[kc][tt] = *(const f16x8*)(wib + (size_t)col * NH + kc * 32 + kg * 8);
      }
    }
  }

  char* lds0 = (char*)&hbuf[0][0];
  // zero h buffer 0 (h0 = 0)
  {
    f32x4 z = {0.f, 0.f, 0.f, 0.f};
    *(f32x4*)(lds0 + threadIdx.x * 16) = z;
  }
  __syncthreads();

  float c[2][4] = {{0, 0, 0, 0}, {0, 0, 0, 0}};

  // precomputed swizzled LDS byte offsets (constant across t)
  int rdo[4];
#pragma unroll
  for (int kc = 0; kc < 4; kc++) {
    const int colb = (kc * 32 + kg * 8) * 2;
    rdo[kc] = lr * 256 + (colb ^ ((lr & 7) << 4));
  }
  int wro[2][4];
#pragma unroll
  for (int nt = 0; nt < 2; nt++)
#pragma unroll
    for (int jr = 0; jr < 4; jr++) {
      const int hrow = kg * 4 + jr;
      const int hcol = w * 32 + nt * 16 + lr;
      wro[nt][jr] = hrow * 256 + ((hcol * 2) ^ ((hrow & 7) << 4));
    }

  // prime x for t=0
  f16x8 axc[4];
  {
    const f16* xp = xptr(0);
#pragma unroll
    for (int kc = 0; kc < 4; kc++) axc[kc] = *(const f16x8*)(xp + kc * 32);
  }

  int cur = 0;
  for (int t = 0; t < len; t++) {
    char* rb = lds0 + cur * 4096;
    f16x8 ah[4];
#pragma unroll
    for (int kc = 0; kc < 4; kc++) ah[kc] = *(const f16x8*)(rb + rdo[kc]);

    // prefetch next-step x into registers (hidden under MFMA+gates+barrier)
    f16x8 axn[4];
    if (t + 1 < len) {
      const f16* xp = xptr(t + 1);
#pragma unroll
      for (int kc = 0; kc < 4; kc++) axn[kc] = *(const f16x8*)(xp + kc * 32);
    }

    f32x4 acc[8];
#pragma unroll
    for (int tt = 0; tt < 8; tt++) {
      f32x4 binit = {bias[tt], bias[tt], bias[tt], bias[tt]};
      acc[tt] = binit;
    }
#pragma unroll
    for (int kc = 0; kc < 4; kc++)
#pragma unroll
      for (int tt = 0; tt < 8; tt++)
        acc[tt] = __builtin_amdgcn_mfma_f32_16x16x32_f16(ah[kc], Wh[kc][tt], acc[tt], 0, 0, 0);
#pragma unroll
    for (int kc = 0; kc < 4; kc++)
#pragma unroll
      for (int tt = 0; tt < 8; tt++)
        acc[tt] = __builtin_amdgcn_mfma_f32_16x16x32_f16(axc[kc], Wi[kc][tt], acc[tt], 0, 0, 0);

    // gates: acc[g*2+nt], g = 0:i 1:f 2:g 3:o
    char* wb = lds0 + (cur ^ 1) * 4096;
#pragma unroll
    for (int nt = 0; nt < 2; nt++) {
#pragma unroll
      for (int jr = 0; jr < 4; jr++) {
        const float iv = acc[0 + nt][jr];
        const float fv = acc[2 + nt][jr];
        const float gv = acc[4 + nt][jr];
        const float ov = acc[6 + nt][jr];
        const float cn = sigf(fv) * c[nt][jr] + sigf(iv) * tanh_fast(gv);
        c[nt][jr] = cn;
        const float hn = sigf(ov) * tanh_fast(cn);
        *(f16*)(wb + wro[nt][jr]) = (f16)hn;
      }
    }
    __syncthreads();
#pragma unroll
    for (int kc = 0; kc < 4; kc++) axc[kc] = axn[kc];
    cur ^= 1;
  }

  // ---- head: out = tanh(h @ W1^T + b1) @ W2^T + b2 ----
  {
    char* rb = lds0 + cur * 4096;
    f16x8 ah[4];
#pragma unroll
    for (int kc = 0; kc < 4; kc++) ah[kc] = *(const f16x8*)(rb + rdo[kc]);
    const float* W1 = hW1 + (size_t)k * NH * NH;
    f32x4 hacc[2];
#pragma unroll
    for (int nt = 0; nt < 2; nt++) {
      const float b1 = hb1[k * NH + w * 32 + nt * 16 + lr];
      f32x4 binit = {b1, b1, b1, b1};
      hacc[nt] = binit;
    }
#pragma unroll
    for (int kc = 0; kc < 4; kc++) {
#pragma unroll
      for (int nt = 0; nt < 2; nt++) {
        const int col = w * 32 + nt * 16 + lr;
        const float* wrow = W1 + (size_t)col * NH + kc * 32 + kg * 8;
        const f32x4 w0 = *(const f32x4*)(wrow);
        const f32x4 w1 = *(const f32x4*)(wrow + 4);
        f16x8 wv;
        wv[0] = (f16)w0[0]; wv[1] = (f16)w0[1]; wv[2] = (f16)w0[2]; wv[3] = (f16)w0[3];
        wv[4] = (f16)w1[0]; wv[5] = (f16)w1[1]; wv[6] = (f16)w1[2]; wv[7] = (f16)w1[3];
        hacc[nt] = __builtin_amdgcn_mfma_f32_16x16x32_f16(ah[kc], wv, hacc[nt], 0, 0, 0);
      }
    }
#pragma unroll
    for (int nt = 0; nt < 2; nt++)
#pragma unroll
      for (int jr = 0; jr < 4; jr++)
        hu[(kg * 4 + jr) * NH + w * 32 + nt * 16 + lr] = tanh_fast(hacc[nt][jr]);
  }
  __syncthreads();
  if (w == 0) {
    const int b = l >> 2, part = l & 3;
    const float* W2 = hW2 + (size_t)k * NH;
    float s = 0.f;
#pragma unroll
    for (int j = 0; j < 32; j++)
      s += hu[b * NH + part * 32 + j] * W2[part * 32 + j];
    s += __shfl_xor(s, 1);
    s += __shfl_xor(s, 2);
    if (part == 0) out[k * NB + b0 + b] = s + hb2[k];
  }
}

// ------------------------------------------------------------- launch -------
extern "C" void kernel_launch(void* const* d_in, const int* in_sizes, int n_in,
                              void* d_out, int out_size, void* d_ws, size_t ws_size,
                              hipStream_t stream) {
  (void)in_sizes; (void)n_in; (void)out_size; (void)ws_size;
  const float* x = (const float*)d_in[0];
  const float* t0 = (const float*)d_in[1];
  const float* node = (const float*)d_in[2];
  const float* tau = (const float*)d_in[3];
  const float* endi = (const float*)d_in[4];
  const float* coords = (const float*)d_in[5];
  const float* Wx1 = (const float*)d_in[6];
  const float* Wx2 = (const float*)d_in[7];
  const float* bx2 = (const float*)d_in[8];
  const float* Wres = (const float*)d_in[9];
  const float* bres = (const float*)d_in[10];
  const float* Wnode = (const float*)d_in[11];
  const float* Wtau = (const float*)d_in[12];
  const float* btau = (const float*)d_in[13];
  const float* Wend1 = (const float*)d_in[14];
  const float* Wend2 = (const float*)d_in[15];
  const float* bend2 = (const float*)d_in[16];
  const float* Wcoord = (const float*)d_in[17];
  const float* Wih = (const float*)d_in[18];
  const float* Whh = (const float*)d_in[19];
  const float* bih = (const float*)d_in[20];
  const float* bhh = (const float*)d_in[21];
  const float* hW1 = (const float*)d_in[22];
  const float* hb1 = (const float*)d_in[23];
  const float* hW2 = (const float*)d_in[24];
  const float* hb2 = (const float*)d_in[25];

  char* ws = (char*)d_ws;
  f16* xh = (f16*)ws;      ws += (size_t)NB * NH * 2;
  f16* t0h = (f16*)ws;     ws += (size_t)NB * NH * 2;
  f16* endh = (f16*)ws;    ws += (size_t)NB * NH * 2;
  f16* tauh = (f16*)ws;    ws += (size_t)NB * NL * NH * 2;
  f16* nodeh = (f16*)ws;   ws += (size_t)NB * 2 * NL * NH * 2;
  f16* coordh = (f16*)ws;  ws += (size_t)NB * 2 * NL * NH * 2;
  f16* Wf = (f16*)ws;      ws += (size_t)NSTEP * 4096 * 2;
  f16* Wih16 = (f16*)ws;   ws += (size_t)7 * 512 * NH * 2;
  f16* Whh16 = (f16*)ws;   ws += (size_t)7 * 512 * NH * 2;
  float* bsum = (float*)ws;

  prep_kernel<<<1024, 256, 0, stream>>>(
      x, t0, tau, endi, coords, Wx1, Wx2, bx2, Wres, bres, Wnode, Wtau, btau,
      Wend1, Wend2, bend2, Wcoord, Wih, Whh, bih, bhh,
      xh, t0h, endh, tauh, coordh, Wf, Wih16, Whh16, bsum);
  node_gemm<<<256, 512, 0, stream>>>(node, Wf, nodeh);
  lstm_run<<<224, 256, 0, stream>>>(xh, t0h, endh, tauh, nodeh, coordh,
                                    Wih16, Whh16, bsum, hW1, hb1, hW2, hb2,
                                    (float*)d_out);
}

// Round 4
// 420.056 us; speedup vs baseline: 1.3407x; 1.0357x over previous
//
#include <hip/hip_runtime.h>
#include <hip/hip_fp16.h>

typedef _Float16 f16;
typedef _Float16 f16x8 __attribute__((ext_vector_type(8)));
typedef float f32x4 __attribute__((ext_vector_type(4)));

#define NB 512
#define NL 16
#define NK 10000
#define NH 128
#define NSTEP 313  // ceil(10000/32), zero-padded K

__device__ __forceinline__ float fast_exp2(float x) {
#if __has_builtin(__builtin_amdgcn_exp2f)
  return __builtin_amdgcn_exp2f(x);
#else
  return exp2f(x);
#endif
}
__device__ __forceinline__ float fast_rcp(float x) {
#if __has_builtin(__builtin_amdgcn_rcpf)
  return __builtin_amdgcn_rcpf(x);
#else
  return 1.f / x;
#endif
}
__device__ __forceinline__ float sigf(float x) {
  return fast_rcp(1.f + fast_exp2(-1.44269504f * x));
}
__device__ __forceinline__ float tanh_fast(float x) {
  return 2.f * fast_rcp(1.f + fast_exp2(-2.88539008f * x)) - 1.f;
}

// ---------------------------------------------------------------- prep ------
// Wf: B in MFMA-fragment order: [s][nt][lane][e] with lane=(kg*16+lr),
// value = Wnode[col=nt*16+lr][k=s*32+kg*8+e], zero-padded past K=10000.
__global__ void prep_kernel(
    const float* __restrict__ x, const float* __restrict__ t0,
    const float* __restrict__ tau, const float* __restrict__ endi,
    const float* __restrict__ coords,
    const float* __restrict__ Wx1, const float* __restrict__ Wx2,
    const float* __restrict__ bx2, const float* __restrict__ Wres,
    const float* __restrict__ bres, const float* __restrict__ Wnode,
    const float* __restrict__ Wtau, const float* __restrict__ btau,
    const float* __restrict__ Wend1, const float* __restrict__ Wend2,
    const float* __restrict__ bend2, const float* __restrict__ Wcoord,
    const float* __restrict__ Wih, const float* __restrict__ Whh,
    const float* __restrict__ bih, const float* __restrict__ bhh,
    f16* __restrict__ xh, f16* __restrict__ t0h, f16* __restrict__ endh,
    f16* __restrict__ tauh, f16* __restrict__ coordh, f16* __restrict__ Wf,
    f16* __restrict__ Wih16, f16* __restrict__ Whh16, float* __restrict__ bsum) {
  const int tid0 = blockIdx.x * blockDim.x + threadIdx.x;
  const int stride = gridDim.x * blockDim.x;

  const int nWf = NSTEP * 4096;     // 1,282,048
  const int nW = 7 * 512 * NH;      // 458,752
  const int nb = 7 * 512;
  const int nxh = NB * NH;          // 65,536
  const int ntau = NB * NL * NH;    // 1,048,576
  const int nco = NB * 2 * NL * NH; // 2,097,152

  for (int i = tid0; i < nWf; i += stride) {
    const int s = i >> 12, r = i & 4095;
    const int nt = r >> 9, l2 = r & 511;
    const int lane = l2 >> 3, e = l2 & 7;
    const int kg = lane >> 4, lr = lane & 15;
    const int col = nt * 16 + lr;
    const int k = s * 32 + kg * 8 + e;
    Wf[i] = (k < NK) ? (f16)Wnode[(size_t)col * NK + k] : (f16)0.f;
  }
  for (int i = tid0; i < nW; i += stride) {
    Wih16[i] = (f16)Wih[i];
    Whh16[i] = (f16)Whh[i];
  }
  for (int i = tid0; i < nb; i += stride) bsum[i] = bih[i] + bhh[i];
  for (int i = tid0; i < nxh; i += stride) {
    const int b = i >> 7, h = i & 127;
    const float s = x[2 * b] * Wx1[0] + x[2 * b + 1] * Wx1[1];
    xh[i] = (f16)tanhf(s * Wx2[h] + bx2[h]);
    t0h[i] = (f16)tanhf(t0[b] * Wres[h] + bres[h]);
    const float e = endi[2 * b] * Wend1[0] + endi[2 * b + 1] * Wend1[1];
    endh[i] = (f16)(e * Wend2[h] + bend2[h]);
  }
  for (int i = tid0; i < ntau; i += stride) {
    const int h = i & 127, bl = i >> 7;
    tauh[i] = (f16)tanhf(tau[bl] * Wtau[h] + btau[h]);
  }
  for (int i = tid0; i < nco; i += stride) {
    const int h = i & 127, br = i >> 7;
    coordh[i] = (f16)(coords[2 * br] * Wcoord[2 * h] +
                      coords[2 * br + 1] * Wcoord[2 * h + 1]);
  }
}

// ------------------------------------------------------------ node GEMM -----
// C(16384x128) = A(16384x10000,f32) * W^T, W pre-arranged as fragments (Wf).
// 512 thr = 8 waves: wave = (kw<<2)|mw. mw picks 16-row subtile, kw splits K
// in halves (157/156 steps). Depth-2 software pipeline via 3-buffer rotation
// (no register copies). No main-loop barriers; LDS reduce at epilogue.
__global__ __launch_bounds__(512, 2) void node_gemm(const float* __restrict__ A,
                                                    const f16* __restrict__ Wf,
                                                    f16* __restrict__ Cn) {
  __shared__ float hred[4][16][132];
  const int w = threadIdx.x >> 6;
  const int l = threadIdx.x & 63;
  const int lr = l & 15, kg = l >> 4;
  const int mw = w & 3, kw = w >> 2;
  const int r0 = blockIdx.x * 64 + mw * 16;
  const int s0 = kw ? 157 : 0;
  const int ns = kw ? 156 : 157;
  const int badstep = kw ? 155 : -1;  // local step holding k>=10000 (kg>=2)
  const float* __restrict__ arow =
      A + (size_t)(r0 + lr) * NK + (size_t)s0 * 32 + kg * 8;
  const f16* __restrict__ bbase = Wf + (size_t)s0 * 4096 + l * 8;

  f32x4 acc[8];
#pragma unroll
  for (int nt = 0; nt < 8; nt++) {
    f32x4 z = {0.f, 0.f, 0.f, 0.f};
    acc[nt] = z;
  }

  f16x8 B0[8], B1[8], B2[8];
  f32x4 A00, A01, A10, A11, A20, A21;

  auto loadpair = [&](int sidx, f32x4& a0, f32x4& a1, f16x8* bq) {
    const f32x4 z = {0.f, 0.f, 0.f, 0.f};
    const float* an = arow + (size_t)sidx * 32;
    if (sidx != badstep || kg < 2) {
      a0 = __builtin_nontemporal_load((const f32x4*)an);
      a1 = __builtin_nontemporal_load((const f32x4*)(an + 4));
    } else {
      a0 = z;
      a1 = z;
    }
    const f16* bn = bbase + (size_t)sidx * 4096;
#pragma unroll
    for (int nt = 0; nt < 8; nt++) bq[nt] = *(const f16x8*)(bn + nt * 512);
  };

  auto domfma = [&](const f32x4& a0, const f32x4& a1, const f16x8* bq) {
    f16x8 av;
    av[0] = (f16)a0[0]; av[1] = (f16)a0[1]; av[2] = (f16)a0[2]; av[3] = (f16)a0[3];
    av[4] = (f16)a1[0]; av[5] = (f16)a1[1]; av[6] = (f16)a1[2]; av[7] = (f16)a1[3];
#pragma unroll
    for (int nt = 0; nt < 8; nt++)
      acc[nt] = __builtin_amdgcn_mfma_f32_16x16x32_f16(av, bq[nt], acc[nt], 0, 0, 0);
  };

  loadpair(0, A00, A01, B0);
  loadpair(1, A10, A11, B1);

  for (int s = 0; s < ns; s += 3) {
    // sub0: consume s, issue s+2
    if (s + 2 < ns) loadpair(s + 2, A20, A21, B2);
    domfma(A00, A01, B0);
    // sub1: consume s+1, issue s+3
    if (s + 1 < ns) {
      if (s + 3 < ns) loadpair(s + 3, A00, A01, B0);
      domfma(A10, A11, B1);
    }
    // sub2: consume s+2, issue s+4
    if (s + 2 < ns) {
      if (s + 4 < ns) loadpair(s + 4, A10, A11, B1);
      domfma(A20, A21, B2);
    }
  }

  // K-split reduce: kw=1 -> LDS, kw=0 adds and stores.
  if (kw == 1) {
#pragma unroll
    for (int nt = 0; nt < 8; nt++)
#pragma unroll
      for (int jr = 0; jr < 4; jr++)
        hred[mw][kg * 4 + jr][nt * 16 + lr] = acc[nt][jr];
  }
  __syncthreads();
  if (kw == 0) {
    f16* crow = Cn + (size_t)(r0 + kg * 4) * NH + lr;
#pragma unroll
    for (int nt = 0; nt < 8; nt++)
#pragma unroll
      for (int jr = 0; jr < 4; jr++) {
        const float v = acc[nt][jr] + hred[mw][kg * 4 + jr][nt * 16 + lr];
        crow[(size_t)jr * NH + nt * 16] = (f16)v;
      }
  }
}

// --------------------------------------------------------------- LSTM -------
// grid: 7 k's x 32 batch-chunks of 16. One wg = 8 waves (512 thr); wave w
// owns hidden units [w*16, w*16+16) across all four gates (4 gate-tiles).
// Wih/Whh fragments in VGPRs (~128), x prefetched 1 step ahead.
__global__ __launch_bounds__(512, 2) void lstm_run(
    const f16* __restrict__ xh, const f16* __restrict__ t0h,
    const f16* __restrict__ endh, const f16* __restrict__ tauh,
    const f16* __restrict__ nodeh, const f16* __restrict__ coordh,
    const f16* __restrict__ Wih16, const f16* __restrict__ Whh16,
    const float* __restrict__ bsum, const float* __restrict__ hW1,
    const float* __restrict__ hb1, const float* __restrict__ hW2,
    const float* __restrict__ hb2, float* __restrict__ out) {
  __shared__ f16 hbuf[2][16 * NH];  // double-buffered h, XOR-swizzled bytes
  __shared__ float hu[16 * NH];

  const int k = blockIdx.x >> 5;
  const int b0 = (blockIdx.x & 31) << 4;
  const int w = threadIdx.x >> 6;
  const int l = threadIdx.x & 63;
  const int lr = l & 15, kg = l >> 4;

  int len;
  switch (k) {
    case 0: len = 83; break;
    case 1: len = 19; break;
    case 2: len = 32; break;
    case 3: len = 32; break;
    case 4: len = 51; break;
    case 5: len = 64; break;
    default: len = 51; break;
  }

  // per-step input fragment pointer (wave-uniform select logic)
  auto xptr = [&](int t) -> const f16* {
    const f16* cb; int bstr, idx;
    if (k == 2) { cb = nodeh; bstr = 32 * NH; idx = t; }
    else if (k == 3) { cb = coordh; bstr = 32 * NH; idx = t; }
    else if (k == 5) {
      const int q = t >> 2, r = t & 3;
      cb = (r == 0 || r == 2) ? nodeh : coordh;
      bstr = 32 * NH;
      idx = 2 * q + ((r >= 2) ? 1 : 0);
    } else {
      if (t == 0) { cb = xh; bstr = NH; idx = 0; }
      else if (t == 1) { cb = t0h; bstr = NH; idx = 0; }
      else if (t == len - 1) { cb = endh; bstr = NH; idx = 0; }
      else {
        const int u = t - 2;
        if (k == 0) {
          const int q = u / 5, r = u - 5 * q;
          if (r == 0) { cb = tauh; bstr = 16 * NH; idx = q; }
          else if (r == 1) { cb = nodeh; bstr = 32 * NH; idx = 2 * q; }
          else if (r == 2) { cb = coordh; bstr = 32 * NH; idx = 2 * q; }
          else if (r == 3) { cb = nodeh; bstr = 32 * NH; idx = 2 * q + 1; }
          else { cb = coordh; bstr = 32 * NH; idx = 2 * q + 1; }
        } else if (k == 1) { cb = tauh; bstr = 16 * NH; idx = u; }
        else if (k == 4) {
          const int q = u / 3, r = u - 3 * q;
          if (r == 0) { cb = tauh; bstr = 16 * NH; idx = q; }
          else { cb = nodeh; bstr = 32 * NH; idx = 2 * q + (r - 1); }
        } else {  // k == 6
          const int q = u / 3, r = u - 3 * q;
          if (r == 0) { cb = tauh; bstr = 16 * NH; idx = q; }
          else { cb = coordh; bstr = 32 * NH; idx = 2 * q + (r - 1); }
        }
      }
    }
    return cb + (size_t)(b0 + lr) * bstr + idx * NH + kg * 8;
  };

  // ---- load weight fragments into registers ----
  // wave w owns hidden cols [w*16, w*16+16); gate g's row block = g*128.
  f16x8 Wh[4][4], Wi[4][4];
  float bias[4];
  {
    const f16* whb = Whh16 + (size_t)k * 512 * NH;
    const f16* wib = Wih16 + (size_t)k * 512 * NH;
#pragma unroll
    for (int g = 0; g < 4; g++) {
      const int col = g * 128 + w * 16 + lr;
      bias[g] = bsum[k * 512 + col];
#pragma unroll
      for (int kc = 0; kc < 4; kc++) {
        Wh[kc][g] = *(const f16x8*)(whb + (size_t)col * NH + kc * 32 + kg * 8);
        Wi[kc][g] = *(const f16x8*)(wib + (size_t)col * NH + kc * 32 + kg * 8);
      }
    }
  }

  char* lds0 = (char*)&hbuf[0][0];
  // zero h buffer 0 (h0 = 0): 512 threads x 8 B = 4096 B
  *(unsigned long long*)(lds0 + threadIdx.x * 8) = 0ull;
  __syncthreads();

  float c[4] = {0, 0, 0, 0};

  // precomputed swizzled LDS byte offsets (constant across t)
  int rdo[4];
#pragma unroll
  for (int kc = 0; kc < 4; kc++) {
    const int colb = (kc * 32 + kg * 8) * 2;
    rdo[kc] = lr * 256 + (colb ^ ((lr & 7) << 4));
  }
  int wro[4];
#pragma unroll
  for (int jr = 0; jr < 4; jr++) {
    const int hrow = kg * 4 + jr;
    const int hcol = w * 16 + lr;
    wro[jr] = hrow * 256 + ((hcol * 2) ^ ((hrow & 7) << 4));
  }

  // prime x for t=0
  f16x8 axc[4];
  {
    const f16* xp = xptr(0);
#pragma unroll
    for (int kc = 0; kc < 4; kc++) axc[kc] = *(const f16x8*)(xp + kc * 32);
  }

  int cur = 0;
  for (int t = 0; t < len; t++) {
    char* rb = lds0 + cur * 4096;
    f16x8 ah[4];
#pragma unroll
    for (int kc = 0; kc < 4; kc++) ah[kc] = *(const f16x8*)(rb + rdo[kc]);

    // prefetch next-step x into registers (hidden under MFMA+gates+barrier)
    f16x8 axn[4];
    if (t + 1 < len) {
      const f16* xp = xptr(t + 1);
#pragma unroll
      for (int kc = 0; kc < 4; kc++) axn[kc] = *(const f16x8*)(xp + kc * 32);
    }

    f32x4 acc[4];
#pragma unroll
    for (int g = 0; g < 4; g++) {
      f32x4 binit = {bias[g], bias[g], bias[g], bias[g]};
      acc[g] = binit;
    }
#pragma unroll
    for (int kc = 0; kc < 4; kc++)
#pragma unroll
      for (int g = 0; g < 4; g++)
        acc[g] = __builtin_amdgcn_mfma_f32_16x16x32_f16(ah[kc], Wh[kc][g], acc[g], 0, 0, 0);
#pragma unroll
    for (int kc = 0; kc < 4; kc++)
#pragma unroll
      for (int g = 0; g < 4; g++)
        acc[g] = __builtin_amdgcn_mfma_f32_16x16x32_f16(axc[kc], Wi[kc][g], acc[g], 0, 0, 0);

    // gates: acc[0]=i acc[1]=f acc[2]=g acc[3]=o
    char* wb = lds0 + (cur ^ 1) * 4096;
#pragma unroll
    for (int jr = 0; jr < 4; jr++) {
      const float iv = acc[0][jr];
      const float fv = acc[1][jr];
      const float gv = acc[2][jr];
      const float ov = acc[3][jr];
      const float cn = sigf(fv) * c[jr] + sigf(iv) * tanh_fast(gv);
      c[jr] = cn;
      const float hn = sigf(ov) * tanh_fast(cn);
      *(f16*)(wb + wro[jr]) = (f16)hn;
    }
    __syncthreads();
#pragma unroll
    for (int kc = 0; kc < 4; kc++) axc[kc] = axn[kc];
    cur ^= 1;
  }

  // ---- head: out = tanh(h @ W1^T + b1) @ W2^T + b2 ----
  {
    char* rb = lds0 + cur * 4096;
    f16x8 ah[4];
#pragma unroll
    for (int kc = 0; kc < 4; kc++) ah[kc] = *(const f16x8*)(rb + rdo[kc]);
    const float* W1 = hW1 + (size_t)k * NH * NH;
    const int col = w * 16 + lr;
    f32x4 hacc;
    {
      const float b1 = hb1[k * NH + col];
      f32x4 binit = {b1, b1, b1, b1};
      hacc = binit;
    }
#pragma unroll
    for (int kc = 0; kc < 4; kc++) {
      const float* wrow = W1 + (size_t)col * NH + kc * 32 + kg * 8;
      const f32x4 w0 = *(const f32x4*)(wrow);
      const f32x4 w1 = *(const f32x4*)(wrow + 4);
      f16x8 wv;
      wv[0] = (f16)w0[0]; wv[1] = (f16)w0[1]; wv[2] = (f16)w0[2]; wv[3] = (f16)w0[3];
      wv[4] = (f16)w1[0]; wv[5] = (f16)w1[1]; wv[6] = (f16)w1[2]; wv[7] = (f16)w1[3];
      hacc = __builtin_amdgcn_mfma_f32_16x16x32_f16(ah[kc], wv, hacc, 0, 0, 0);
    }
#pragma unroll
    for (int jr = 0; jr < 4; jr++)
      hu[(kg * 4 + jr) * NH + col] = tanh_fast(hacc[jr]);
  }
  __syncthreads();
  if (w == 0) {
    const int b = l >> 2, part = l & 3;
    const float* W2 = hW2 + (size_t)k * NH;
    float s = 0.f;
#pragma unroll
    for (int j = 0; j < 32; j++)
      s += hu[b * NH + part * 32 + j] * W2[part * 32 + j];
    s += __shfl_xor(s, 1);
    s += __shfl_xor(s, 2);
    if (part == 0) out[k * NB + b0 + b] = s + hb2[k];
  }
}

// ------------------------------------------------------------- launch -------
extern "C" void kernel_launch(void* const* d_in, const int* in_sizes, int n_in,
                              void* d_out, int out_size, void* d_ws, size_t ws_size,
                              hipStream_t stream) {
  (void)in_sizes; (void)n_in; (void)out_size; (void)ws_size;
  const float* x = (const float*)d_in[0];
  const float* t0 = (const float*)d_in[1];
  const float* node = (const float*)d_in[2];
  const float* tau = (const float*)d_in[3];
  const float* endi = (const float*)d_in[4];
  const float* coords = (const float*)d_in[5];
  const float* Wx1 = (const float*)d_in[6];
  const float* Wx2 = (const float*)d_in[7];
  const float* bx2 = (const float*)d_in[8];
  const float* Wres = (const float*)d_in[9];
  const float* bres = (const float*)d_in[10];
  const float* Wnode = (const float*)d_in[11];
  const float* Wtau = (const float*)d_in[12];
  const float* btau = (const float*)d_in[13];
  const float* Wend1 = (const float*)d_in[14];
  const float* Wend2 = (const float*)d_in[15];
  const float* bend2 = (const float*)d_in[16];
  const float* Wcoord = (const float*)d_in[17];
  const float* Wih = (const float*)d_in[18];
  const float* Whh = (const float*)d_in[19];
  const float* bih = (const float*)d_in[20];
  const float* bhh = (const float*)d_in[21];
  const float* hW1 = (const float*)d_in[22];
  const float* hb1 = (const float*)d_in[23];
  const float* hW2 = (const float*)d_in[24];
  const float* hb2 = (const float*)d_in[25];

  char* ws = (char*)d_ws;
  f16* xh = (f16*)ws;      ws += (size_t)NB * NH * 2;
  f16* t0h = (f16*)ws;     ws += (size_t)NB * NH * 2;
  f16* endh = (f16*)ws;    ws += (size_t)NB * NH * 2;
  f16* tauh = (f16*)ws;    ws += (size_t)NB * NL * NH * 2;
  f16* nodeh = (f16*)ws;   ws += (size_t)NB * 2 * NL * NH * 2;
  f16* coordh = (f16*)ws;  ws += (size_t)NB * 2 * NL * NH * 2;
  f16* Wf = (f16*)ws;      ws += (size_t)NSTEP * 4096 * 2;
  f16* Wih16 = (f16*)ws;   ws += (size_t)7 * 512 * NH * 2;
  f16* Whh16 = (f16*)ws;   ws += (size_t)7 * 512 * NH * 2;
  float* bsum = (float*)ws;

  prep_kernel<<<1024, 256, 0, stream>>>(
      x, t0, tau, endi, coords, Wx1, Wx2, bx2, Wres, bres, Wnode, Wtau, btau,
      Wend1, Wend2, bend2, Wcoord, Wih, Whh, bih, bhh,
      xh, t0h, endh, tauh, coordh, Wf, Wih16, Whh16, bsum);
  node_gemm<<<256, 512, 0, stream>>>(node, Wf, nodeh);
  lstm_run<<<224, 512, 0, stream>>>(xh, t0h, endh, tauh, nodeh, coordh,
                                    Wih16, Whh16, bsum, hW1, hb1, hW2, hb2,
                                    (float*)d_out);
}

// Round 5
// 409.633 us; speedup vs baseline: 1.3748x; 1.0254x over previous
//
#include <hip/hip_runtime.h>
#include <hip/hip_fp16.h>

typedef _Float16 f16;
typedef _Float16 f16x8 __attribute__((ext_vector_type(8)));
typedef float f32x4 __attribute__((ext_vector_type(4)));

#define NB 512
#define NL 16
#define NK 10000
#define NH 128
#define NSTEP 313  // ceil(10000/32), zero-padded K

__device__ __forceinline__ float fast_exp2(float x) {
#if __has_builtin(__builtin_amdgcn_exp2f)
  return __builtin_amdgcn_exp2f(x);
#else
  return exp2f(x);
#endif
}
__device__ __forceinline__ float fast_rcp(float x) {
#if __has_builtin(__builtin_amdgcn_rcpf)
  return __builtin_amdgcn_rcpf(x);
#else
  return 1.f / x;
#endif
}
__device__ __forceinline__ float sigf(float x) {
  return fast_rcp(1.f + fast_exp2(-1.44269504f * x));
}
__device__ __forceinline__ float tanh_fast(float x) {
  return 2.f * fast_rcp(1.f + fast_exp2(-2.88539008f * x)) - 1.f;
}

// ---------------------------------------------------------------- prep ------
// Wf: B in MFMA-fragment order: [s][nt][lane][e] with lane=(kg*16+lr),
// value = Wnode[col=nt*16+lr][k=s*32+kg*8+e], zero-padded past K=10000.
__global__ void prep_kernel(
    const float* __restrict__ x, const float* __restrict__ t0,
    const float* __restrict__ tau, const float* __restrict__ endi,
    const float* __restrict__ coords,
    const float* __restrict__ Wx1, const float* __restrict__ Wx2,
    const float* __restrict__ bx2, const float* __restrict__ Wres,
    const float* __restrict__ bres, const float* __restrict__ Wnode,
    const float* __restrict__ Wtau, const float* __restrict__ btau,
    const float* __restrict__ Wend1, const float* __restrict__ Wend2,
    const float* __restrict__ bend2, const float* __restrict__ Wcoord,
    const float* __restrict__ Wih, const float* __restrict__ Whh,
    const float* __restrict__ bih, const float* __restrict__ bhh,
    f16* __restrict__ xh, f16* __restrict__ t0h, f16* __restrict__ endh,
    f16* __restrict__ tauh, f16* __restrict__ coordh, f16* __restrict__ Wf,
    f16* __restrict__ Wih16, f16* __restrict__ Whh16, float* __restrict__ bsum) {
  const int tid0 = blockIdx.x * blockDim.x + threadIdx.x;
  const int stride = gridDim.x * blockDim.x;

  const int nWf = NSTEP * 4096;     // 1,282,048
  const int nW = 7 * 512 * NH;      // 458,752
  const int nb = 7 * 512;
  const int nxh = NB * NH;          // 65,536
  const int ntau = NB * NL * NH;    // 1,048,576
  const int nco = NB * 2 * NL * NH; // 2,097,152

  for (int i = tid0; i < nWf; i += stride) {
    const int s = i >> 12, r = i & 4095;
    const int nt = r >> 9, l2 = r & 511;
    const int lane = l2 >> 3, e = l2 & 7;
    const int kg = lane >> 4, lr = lane & 15;
    const int col = nt * 16 + lr;
    const int k = s * 32 + kg * 8 + e;
    Wf[i] = (k < NK) ? (f16)Wnode[(size_t)col * NK + k] : (f16)0.f;
  }
  for (int i = tid0; i < nW; i += stride) {
    Wih16[i] = (f16)Wih[i];
    Whh16[i] = (f16)Whh[i];
  }
  for (int i = tid0; i < nb; i += stride) bsum[i] = bih[i] + bhh[i];
  for (int i = tid0; i < nxh; i += stride) {
    const int b = i >> 7, h = i & 127;
    const float s = x[2 * b] * Wx1[0] + x[2 * b + 1] * Wx1[1];
    xh[i] = (f16)tanhf(s * Wx2[h] + bx2[h]);
    t0h[i] = (f16)tanhf(t0[b] * Wres[h] + bres[h]);
    const float e = endi[2 * b] * Wend1[0] + endi[2 * b + 1] * Wend1[1];
    endh[i] = (f16)(e * Wend2[h] + bend2[h]);
  }
  for (int i = tid0; i < ntau; i += stride) {
    const int h = i & 127, bl = i >> 7;
    tauh[i] = (f16)tanhf(tau[bl] * Wtau[h] + btau[h]);
  }
  for (int i = tid0; i < nco; i += stride) {
    const int h = i & 127, br = i >> 7;
    coordh[i] = (f16)(coords[2 * br] * Wcoord[2 * h] +
                      coords[2 * br + 1] * Wcoord[2 * h + 1]);
  }
}

// ------------------------------------------------------------ node GEMM -----
// C(16384x128) = A(16384x10000,f32) * W^T, W pre-arranged as fragments (Wf).
// 512 thr = 8 waves: wave = (kw<<2)|mw. mw picks 16-row subtile, kw splits K
// in halves. Branch-free steady-state, depth-3-ahead, 4 static rotation
// slots. OOB K-tail handled by branchless address clamp (B pad is zero).
__global__ __launch_bounds__(512, 2) void node_gemm(const float* __restrict__ A,
                                                    const f16* __restrict__ Wf,
                                                    f16* __restrict__ Cn) {
  __shared__ float hred[4][16][132];
  const int w = threadIdx.x >> 6;
  const int l = threadIdx.x & 63;
  const int lr = l & 15, kg = l >> 4;
  const int mw = w & 3, kw = w >> 2;
  const int r0 = blockIdx.x * 64 + mw * 16;
  const int s0 = kw ? 157 : 0;   // global K-step base
  const int ns = kw ? 156 : 157; // local step count
  const float* __restrict__ arow =
      A + (size_t)(r0 + lr) * NK + (size_t)s0 * 32 + kg * 8;
  // clamp (in floats, relative to arow) keeping loads in-bounds & 16B-aligned;
  // clamped lanes read garbage that multiplies Wf's zero pad -> contributes 0.
  const int offmax = 9992 - s0 * 32 - kg * 8;
  const f16* __restrict__ bbase = Wf + (size_t)s0 * 4096 + l * 8;

  f32x4 acc[8];
#pragma unroll
  for (int nt = 0; nt < 8; nt++) {
    f32x4 z = {0.f, 0.f, 0.f, 0.f};
    acc[nt] = z;
  }

  f32x4 A0a, A0b, A1a, A1b, A2a, A2b, A3a, A3b;
  f16x8 B0[8], B1[8], B2[8], B3[8];

  auto lp = [&](int sidx, f32x4& a0, f32x4& a1, f16x8* bq) {
    int off = sidx * 32;
    off = off > offmax ? offmax : off;
    const float* an = arow + off;
    a0 = __builtin_nontemporal_load((const f32x4*)an);
    a1 = __builtin_nontemporal_load((const f32x4*)(an + 4));
    const f16* bn = bbase + (size_t)sidx * 4096;
#pragma unroll
    for (int nt = 0; nt < 8; nt++) bq[nt] = *(const f16x8*)(bn + nt * 512);
  };

  auto domfma = [&](const f32x4& a0, const f32x4& a1, const f16x8* bq) {
    f16x8 av;
    av[0] = (f16)a0[0]; av[1] = (f16)a0[1]; av[2] = (f16)a0[2]; av[3] = (f16)a0[3];
    av[4] = (f16)a1[0]; av[5] = (f16)a1[1]; av[6] = (f16)a1[2]; av[7] = (f16)a1[3];
#pragma unroll
    for (int nt = 0; nt < 8; nt++)
      acc[nt] = __builtin_amdgcn_mfma_f32_16x16x32_f16(av, bq[nt], acc[nt], 0, 0, 0);
  };

  // prologue: prime 3 slots
  lp(0, A0a, A0b, B0);
  lp(1, A1a, A1b, B1);
  lp(2, A2a, A2b, B2);

  int sb = 0;
  for (; sb + 6 < ns; sb += 4) {
    lp(sb + 3, A3a, A3b, B3); domfma(A0a, A0b, B0);
    lp(sb + 4, A0a, A0b, B0); domfma(A1a, A1b, B1);
    lp(sb + 5, A1a, A1b, B1); domfma(A2a, A2b, B2);
    lp(sb + 6, A2a, A2b, B2); domfma(A3a, A3b, B3);
  }
  // tail: r in [3,6]; slots hold sb, sb+1, sb+2
  {
    const int r = ns - sb;
    if (r > 3) lp(sb + 3, A3a, A3b, B3);
    domfma(A0a, A0b, B0);
    if (r > 4) lp(sb + 4, A0a, A0b, B0);
    domfma(A1a, A1b, B1);
    if (r > 5) lp(sb + 5, A1a, A1b, B1);
    domfma(A2a, A2b, B2);
    if (r > 3) domfma(A3a, A3b, B3);
    if (r > 4) domfma(A0a, A0b, B0);
    if (r > 5) domfma(A1a, A1b, B1);
  }

  // K-split reduce: kw=1 -> LDS, kw=0 adds and stores.
  if (kw == 1) {
#pragma unroll
    for (int nt = 0; nt < 8; nt++)
#pragma unroll
      for (int jr = 0; jr < 4; jr++)
        hred[mw][kg * 4 + jr][nt * 16 + lr] = acc[nt][jr];
  }
  __syncthreads();
  if (kw == 0) {
    f16* crow = Cn + (size_t)(r0 + kg * 4) * NH + lr;
#pragma unroll
    for (int nt = 0; nt < 8; nt++)
#pragma unroll
      for (int jr = 0; jr < 4; jr++) {
        const float v = acc[nt][jr] + hred[mw][kg * 4 + jr][nt * 16 + lr];
        crow[(size_t)jr * NH + nt * 16] = (f16)v;
      }
  }
}

// --------------------------------------------------------------- LSTM -------
// grid: 7 k's x 32 batch-chunks of 16. One wg = 8 waves (512 thr); wave w
// owns hidden units [w*16, w*16+16) across all four gates (4 gate-tiles).
// Wih/Whh fragments in VGPRs (~128), x prefetched 1 step ahead. x-MFMAs run
// before h-MFMAs so the ds_read(h) latency hides under them.
__global__ __launch_bounds__(512, 2) void lstm_run(
    const f16* __restrict__ xh, const f16* __restrict__ t0h,
    const f16* __restrict__ endh, const f16* __restrict__ tauh,
    const f16* __restrict__ nodeh, const f16* __restrict__ coordh,
    const f16* __restrict__ Wih16, const f16* __restrict__ Whh16,
    const float* __restrict__ bsum, const float* __restrict__ hW1,
    const float* __restrict__ hb1, const float* __restrict__ hW2,
    const float* __restrict__ hb2, float* __restrict__ out) {
  __shared__ f16 hbuf[2][16 * NH];  // double-buffered h, XOR-swizzled bytes
  __shared__ float hu[16 * NH];

  const int k = blockIdx.x >> 5;
  const int b0 = (blockIdx.x & 31) << 4;
  const int w = threadIdx.x >> 6;
  const int l = threadIdx.x & 63;
  const int lr = l & 15, kg = l >> 4;

  int len;
  switch (k) {
    case 0: len = 83; break;
    case 1: len = 19; break;
    case 2: len = 32; break;
    case 3: len = 32; break;
    case 4: len = 51; break;
    case 5: len = 64; break;
    default: len = 51; break;
  }

  // per-step input fragment pointer (wave-uniform select logic)
  auto xptr = [&](int t) -> const f16* {
    const f16* cb; int bstr, idx;
    if (k == 2) { cb = nodeh; bstr = 32 * NH; idx = t; }
    else if (k == 3) { cb = coordh; bstr = 32 * NH; idx = t; }
    else if (k == 5) {
      const int q = t >> 2, r = t & 3;
      cb = (r == 0 || r == 2) ? nodeh : coordh;
      bstr = 32 * NH;
      idx = 2 * q + ((r >= 2) ? 1 : 0);
    } else {
      if (t == 0) { cb = xh; bstr = NH; idx = 0; }
      else if (t == 1) { cb = t0h; bstr = NH; idx = 0; }
      else if (t == len - 1) { cb = endh; bstr = NH; idx = 0; }
      else {
        const int u = t - 2;
        if (k == 0) {
          const int q = u / 5, r = u - 5 * q;
          if (r == 0) { cb = tauh; bstr = 16 * NH; idx = q; }
          else if (r == 1) { cb = nodeh; bstr = 32 * NH; idx = 2 * q; }
          else if (r == 2) { cb = coordh; bstr = 32 * NH; idx = 2 * q; }
          else if (r == 3) { cb = nodeh; bstr = 32 * NH; idx = 2 * q + 1; }
          else { cb = coordh; bstr = 32 * NH; idx = 2 * q + 1; }
        } else if (k == 1) { cb = tauh; bstr = 16 * NH; idx = u; }
        else if (k == 4) {
          const int q = u / 3, r = u - 3 * q;
          if (r == 0) { cb = tauh; bstr = 16 * NH; idx = q; }
          else { cb = nodeh; bstr = 32 * NH; idx = 2 * q + (r - 1); }
        } else {  // k == 6
          const int q = u / 3, r = u - 3 * q;
          if (r == 0) { cb = tauh; bstr = 16 * NH; idx = q; }
          else { cb = coordh; bstr = 32 * NH; idx = 2 * q + (r - 1); }
        }
      }
    }
    return cb + (size_t)(b0 + lr) * bstr + idx * NH + kg * 8;
  };

  // ---- load weight fragments into registers ----
  // wave w owns hidden cols [w*16, w*16+16); gate g's row block = g*128.
  f16x8 Wh[4][4], Wi[4][4];
  float bias[4];
  {
    const f16* whb = Whh16 + (size_t)k * 512 * NH;
    const f16* wib = Wih16 + (size_t)k * 512 * NH;
#pragma unroll
    for (int g = 0; g < 4; g++) {
      const int col = g * 128 + w * 16 + lr;
      bias[g] = bsum[k * 512 + col];
#pragma unroll
      for (int kc = 0; kc < 4; kc++) {
        Wh[kc][g] = *(const f16x8*)(whb + (size_t)col * NH + kc * 32 + kg * 8);
        Wi[kc][g] = *(const f16x8*)(wib + (size_t)col * NH + kc * 32 + kg * 8);
      }
    }
  }

  char* lds0 = (char*)&hbuf[0][0];
  // zero h buffer 0 (h0 = 0): 512 threads x 8 B = 4096 B
  *(unsigned long long*)(lds0 + threadIdx.x * 8) = 0ull;
  __syncthreads();

  float c[4] = {0, 0, 0, 0};

  // precomputed swizzled LDS byte offsets (constant across t)
  int rdo[4];
#pragma unroll
  for (int kc = 0; kc < 4; kc++) {
    const int colb = (kc * 32 + kg * 8) * 2;
    rdo[kc] = lr * 256 + (colb ^ ((lr & 7) << 4));
  }
  int wro[4];
#pragma unroll
  for (int jr = 0; jr < 4; jr++) {
    const int hrow = kg * 4 + jr;
    const int hcol = w * 16 + lr;
    wro[jr] = hrow * 256 + ((hcol * 2) ^ ((hrow & 7) << 4));
  }

  // prime x for t=0
  f16x8 axc[4];
  {
    const f16* xp = xptr(0);
#pragma unroll
    for (int kc = 0; kc < 4; kc++) axc[kc] = *(const f16x8*)(xp + kc * 32);
  }

  int cur = 0;
  for (int t = 0; t < len; t++) {
    char* rb = lds0 + cur * 4096;
    f16x8 ah[4];
#pragma unroll
    for (int kc = 0; kc < 4; kc++) ah[kc] = *(const f16x8*)(rb + rdo[kc]);

    // prefetch next-step x into registers (hidden under MFMA+gates+barrier)
    f16x8 axn[4];
    if (t + 1 < len) {
      const f16* xp = xptr(t + 1);
#pragma unroll
      for (int kc = 0; kc < 4; kc++) axn[kc] = *(const f16x8*)(xp + kc * 32);
    }

    f32x4 acc[4];
#pragma unroll
    for (int g = 0; g < 4; g++) {
      f32x4 binit = {bias[g], bias[g], bias[g], bias[g]};
      acc[g] = binit;
    }
    // x-part first (register operands ready) -> hides ds_read(h) latency
#pragma unroll
    for (int kc = 0; kc < 4; kc++)
#pragma unroll
      for (int g = 0; g < 4; g++)
        acc[g] = __builtin_amdgcn_mfma_f32_16x16x32_f16(axc[kc], Wi[kc][g], acc[g], 0, 0, 0);
#pragma unroll
    for (int kc = 0; kc < 4; kc++)
#pragma unroll
      for (int g = 0; g < 4; g++)
        acc[g] = __builtin_amdgcn_mfma_f32_16x16x32_f16(ah[kc], Wh[kc][g], acc[g], 0, 0, 0);

    // gates: acc[0]=i acc[1]=f acc[2]=g acc[3]=o
    char* wb = lds0 + (cur ^ 1) * 4096;
#pragma unroll
    for (int jr = 0; jr < 4; jr++) {
      const float iv = acc[0][jr];
      const float fv = acc[1][jr];
      const float gv = acc[2][jr];
      const float ov = acc[3][jr];
      const float cn = sigf(fv) * c[jr] + sigf(iv) * tanh_fast(gv);
      c[jr] = cn;
      const float hn = sigf(ov) * tanh_fast(cn);
      *(f16*)(wb + wro[jr]) = (f16)hn;
    }
    __syncthreads();
#pragma unroll
    for (int kc = 0; kc < 4; kc++) axc[kc] = axn[kc];
    cur ^= 1;
  }

  // ---- head: out = tanh(h @ W1^T + b1) @ W2^T + b2 ----
  {
    char* rb = lds0 + cur * 4096;
    f16x8 ah[4];
#pragma unroll
    for (int kc = 0; kc < 4; kc++) ah[kc] = *(const f16x8*)(rb + rdo[kc]);
    const float* W1 = hW1 + (size_t)k * NH * NH;
    const int col = w * 16 + lr;
    f32x4 hacc;
    {
      const float b1 = hb1[k * NH + col];
      f32x4 binit = {b1, b1, b1, b1};
      hacc = binit;
    }
#pragma unroll
    for (int kc = 0; kc < 4; kc++) {
      const float* wrow = W1 + (size_t)col * NH + kc * 32 + kg * 8;
      const f32x4 w0 = *(const f32x4*)(wrow);
      const f32x4 w1 = *(const f32x4*)(wrow + 4);
      f16x8 wv;
      wv[0] = (f16)w0[0]; wv[1] = (f16)w0[1]; wv[2] = (f16)w0[2]; wv[3] = (f16)w0[3];
      wv[4] = (f16)w1[0]; wv[5] = (f16)w1[1]; wv[6] = (f16)w1[2]; wv[7] = (f16)w1[3];
      hacc = __builtin_amdgcn_mfma_f32_16x16x32_f16(ah[kc], wv, hacc, 0, 0, 0);
    }
#pragma unroll
    for (int jr = 0; jr < 4; jr++)
      hu[(kg * 4 + jr) * NH + col] = tanh_fast(hacc[jr]);
  }
  __syncthreads();
  if (w == 0) {
    const int b = l >> 2, part = l & 3;
    const float* W2 = hW2 + (size_t)k * NH;
    float s = 0.f;
#pragma unroll
    for (int j = 0; j < 32; j++)
      s += hu[b * NH + part * 32 + j] * W2[part * 32 + j];
    s += __shfl_xor(s, 1);
    s += __shfl_xor(s, 2);
    if (part == 0) out[k * NB + b0 + b] = s + hb2[k];
  }
}

// ------------------------------------------------------------- launch -------
extern "C" void kernel_launch(void* const* d_in, const int* in_sizes, int n_in,
                              void* d_out, int out_size, void* d_ws, size_t ws_size,
                              hipStream_t stream) {
  (void)in_sizes; (void)n_in; (void)out_size; (void)ws_size;
  const float* x = (const float*)d_in[0];
  const float* t0 = (const float*)d_in[1];
  const float* node = (const float*)d_in[2];
  const float* tau = (const float*)d_in[3];
  const float* endi = (const float*)d_in[4];
  const float* coords = (const float*)d_in[5];
  const float* Wx1 = (const float*)d_in[6];
  const float* Wx2 = (const float*)d_in[7];
  const float* bx2 = (const float*)d_in[8];
  const float* Wres = (const float*)d_in[9];
  const float* bres = (const float*)d_in[10];
  const float* Wnode = (const float*)d_in[11];
  const float* Wtau = (const float*)d_in[12];
  const float* btau = (const float*)d_in[13];
  const float* Wend1 = (const float*)d_in[14];
  const float* Wend2 = (const float*)d_in[15];
  const float* bend2 = (const float*)d_in[16];
  const float* Wcoord = (const float*)d_in[17];
  const float* Wih = (const float*)d_in[18];
  const float* Whh = (const float*)d_in[19];
  const float* bih = (const float*)d_in[20];
  const float* bhh = (const float*)d_in[21];
  const float* hW1 = (const float*)d_in[22];
  const float* hb1 = (const float*)d_in[23];
  const float* hW2 = (const float*)d_in[24];
  const float* hb2 = (const float*)d_in[25];

  char* ws = (char*)d_ws;
  f16* xh = (f16*)ws;      ws += (size_t)NB * NH * 2;
  f16* t0h = (f16*)ws;     ws += (size_t)NB * NH * 2;
  f16* endh = (f16*)ws;    ws += (size_t)NB * NH * 2;
  f16* tauh = (f16*)ws;    ws += (size_t)NB * NL * NH * 2;
  f16* nodeh = (f16*)ws;   ws += (size_t)NB * 2 * NL * NH * 2;
  f16* coordh = (f16*)ws;  ws += (size_t)NB * 2 * NL * NH * 2;
  f16* Wf = (f16*)ws;      ws += (size_t)NSTEP * 4096 * 2;
  f16* Wih16 = (f16*)ws;   ws += (size_t)7 * 512 * NH * 2;
  f16* Whh16 = (f16*)ws;   ws += (size_t)7 * 512 * NH * 2;
  float* bsum = (float*)ws;

  prep_kernel<<<1024, 256, 0, stream>>>(
      x, t0, tau, endi, coords, Wx1, Wx2, bx2, Wres, bres, Wnode, Wtau, btau,
      Wend1, Wend2, bend2, Wcoord, Wih, Whh, bih, bhh,
      xh, t0h, endh, tauh, coordh, Wf, Wih16, Whh16, bsum);
  node_gemm<<<256, 512, 0, stream>>>(node, Wf, nodeh);
  lstm_run<<<224, 512, 0, stream>>>(xh, t0h, endh, tauh, nodeh, coordh,
                                    Wih16, Whh16, bsum, hW1, hb1, hW2, hb2,
                                    (float*)d_out);
}

// Round 6
// 308.424 us; speedup vs baseline: 1.8260x; 1.3281x over previous
//
#include <hip/hip_runtime.h>
#include <hip/hip_fp16.h>

typedef _Float16 f16;
typedef _Float16 f16x8 __attribute__((ext_vector_type(8)));
typedef _Float16 f16x4 __attribute__((ext_vector_type(4)));
typedef float f32x4 __attribute__((ext_vector_type(4)));

#define NB 512
#define NL 16
#define NK 10000
#define NH 128
#define NSTEP 313  // ceil(10000/32), zero-padded K

__device__ __forceinline__ float fast_exp2(float x) {
#if __has_builtin(__builtin_amdgcn_exp2f)
  return __builtin_amdgcn_exp2f(x);
#else
  return exp2f(x);
#endif
}
__device__ __forceinline__ float fast_rcp(float x) {
#if __has_builtin(__builtin_amdgcn_rcpf)
  return __builtin_amdgcn_rcpf(x);
#else
  return 1.f / x;
#endif
}
__device__ __forceinline__ float sigf(float x) {
  return fast_rcp(1.f + fast_exp2(-1.44269504f * x));
}
__device__ __forceinline__ float tanh_fast(float x) {
  return 2.f * fast_rcp(1.f + fast_exp2(-2.88539008f * x)) - 1.f;
}

__device__ __forceinline__ void gload16(const void* g, void* l) {
  __builtin_amdgcn_global_load_lds(
      (const __attribute__((address_space(1))) unsigned int*)g,
      (__attribute__((address_space(3))) unsigned int*)l, 16, 0, 0);
}

// ---------------------------------------------------------------- prep ------
// Wf: B in MFMA-fragment order: [s][nt][lane][e] with lane=(kg*16+lr),
// value = Wnode[col=nt*16+lr][k=s*32+kg*8+e], zero-padded past K=10000.
__global__ void prep_kernel(
    const float* __restrict__ x, const float* __restrict__ t0,
    const float* __restrict__ tau, const float* __restrict__ endi,
    const float* __restrict__ coords,
    const float* __restrict__ Wx1, const float* __restrict__ Wx2,
    const float* __restrict__ bx2, const float* __restrict__ Wres,
    const float* __restrict__ bres, const float* __restrict__ Wnode,
    const float* __restrict__ Wtau, const float* __restrict__ btau,
    const float* __restrict__ Wend1, const float* __restrict__ Wend2,
    const float* __restrict__ bend2, const float* __restrict__ Wcoord,
    const float* __restrict__ Wih, const float* __restrict__ Whh,
    const float* __restrict__ bih, const float* __restrict__ bhh,
    f16* __restrict__ xh, f16* __restrict__ t0h, f16* __restrict__ endh,
    f16* __restrict__ tauh, f16* __restrict__ coordh, f16* __restrict__ Wf,
    f16* __restrict__ Wih16, f16* __restrict__ Whh16, float* __restrict__ bsum) {
  const int tid0 = blockIdx.x * blockDim.x + threadIdx.x;
  const int stride = gridDim.x * blockDim.x;

  const int nWf = NSTEP * 4096;     // 1,282,048
  const int nW = 7 * 512 * NH;      // 458,752
  const int nb = 7 * 512;
  const int nxh = NB * NH;          // 65,536
  const int ntau = NB * NL * NH;    // 1,048,576
  const int nco = NB * 2 * NL * NH; // 2,097,152

  for (int i = tid0; i < nWf; i += stride) {
    const int s = i >> 12, r = i & 4095;
    const int nt = r >> 9, l2 = r & 511;
    const int lane = l2 >> 3, e = l2 & 7;
    const int kg = lane >> 4, lr = lane & 15;
    const int col = nt * 16 + lr;
    const int k = s * 32 + kg * 8 + e;
    Wf[i] = (k < NK) ? (f16)Wnode[(size_t)col * NK + k] : (f16)0.f;
  }
  for (int i = tid0; i < nW; i += stride) {
    Wih16[i] = (f16)Wih[i];
    Whh16[i] = (f16)Whh[i];
  }
  for (int i = tid0; i < nb; i += stride) bsum[i] = bih[i] + bhh[i];
  for (int i = tid0; i < nxh; i += stride) {
    const int b = i >> 7, h = i & 127;
    const float s = x[2 * b] * Wx1[0] + x[2 * b + 1] * Wx1[1];
    xh[i] = (f16)tanhf(s * Wx2[h] + bx2[h]);
    t0h[i] = (f16)tanhf(t0[b] * Wres[h] + bres[h]);
    const float e = endi[2 * b] * Wend1[0] + endi[2 * b + 1] * Wend1[1];
    endh[i] = (f16)(e * Wend2[h] + bend2[h]);
  }
  for (int i = tid0; i < ntau; i += stride) {
    const int h = i & 127, bl = i >> 7;
    tauh[i] = (f16)tanhf(tau[bl] * Wtau[h] + btau[h]);
  }
  for (int i = tid0; i < nco; i += stride) {
    const int h = i & 127, br = i >> 7;
    coordh[i] = (f16)(coords[2 * br] * Wcoord[2 * h] +
                      coords[2 * br + 1] * Wcoord[2 * h + 1]);
  }
}

// ------------------------------------------------------------ node GEMM -----
// C = A(16384x10000,f32) * W^T via LDS-staged tiles + split-K(4) partials.
// Grid 256 = 64 row-blocks x 4 K-chunks; wg 512 thr = 8 waves; tile =
// 256 rows x 32 k f32 (32 KB), double-buffered. global_load_lds staging with
// pre-swizzled source (XOR row swizzle), counted vmcnt + raw s_barrier
// (no __syncthreads drain). Wave w computes rows [w*32, w*32+32).
__global__ __launch_bounds__(512, 2) void node_gemm(const float* __restrict__ A,
                                                    const f16* __restrict__ Wf,
                                                    float* __restrict__ P) {
  __shared__ char As[2][32768];
  const int tid = threadIdx.x;
  const int w = tid >> 6, l = tid & 63;
  const int lr = l & 15, kg = l >> 4;
  const int c = blockIdx.x & 3;
  const int m = blockIdx.x >> 2;  // 0..63
  const int r0 = m * 256;
  const int ts = (c == 0) ? 0 : 79 + 78 * (c - 1);
  const int te = ts + ((c == 0) ? 79 : 78);

  // staging addresses: 4 issues/lane, each wave writes 4 KB linear LDS.
  const char* Ab = (const char*)A;
  const char* ap[4];
  int bnd[4];
#pragma unroll
  for (int i = 0; i < 4; i++) {
    const int row = w * 32 + i * 8 + (l >> 3);
    const int swz = ((l & 7) * 16) ^ ((row & 7) << 4);
    ap[i] = Ab + (size_t)(r0 + row) * 40000 + swz;
    bnd[i] = 39984 - swz;  // clamp keeps 16B read in-bounds; Wf pad zeros it
  }
  char* lds0 = &As[0][0];

  // swizzled LDS read offsets per sub-tile
  int rdo[2][2];
#pragma unroll
  for (int sub = 0; sub < 2; sub++) {
    const int row = w * 32 + sub * 16 + lr;
#pragma unroll
    for (int h = 0; h < 2; h++)
      rdo[sub][h] = row * 128 + ((kg * 32 + h * 16) ^ ((row & 7) << 4));
  }

  f32x4 acc[2][8];
#pragma unroll
  for (int sub = 0; sub < 2; sub++)
#pragma unroll
    for (int nt = 0; nt < 8; nt++) {
      f32x4 z = {0.f, 0.f, 0.f, 0.f};
      acc[sub][nt] = z;
    }

  auto stage = [&](int t, int buf) {
    const int tb = t * 128;
    char* db = lds0 + buf * 32768 + w * 4096;
#pragma unroll
    for (int i = 0; i < 4; i++) {
      const int off = tb < bnd[i] ? tb : bnd[i];
      gload16(ap[i] + off, db + i * 1024);
    }
  };

  stage(ts, 0);
  asm volatile("s_waitcnt vmcnt(0)" ::: "memory");
  __builtin_amdgcn_s_barrier();

  for (int t = ts; t < te; t++) {
    const int buf = (t - ts) & 1;
    // B fragments for this 32-k step (L1-hot across the 8 waves)
    const f16* bp = Wf + (size_t)t * 4096 + l * 8;
    f16x8 Bv[8];
#pragma unroll
    for (int nt = 0; nt < 8; nt++) Bv[nt] = *(const f16x8*)(bp + nt * 512);
    // prefetch next tile (async DMA; B-use wait sees vmcnt(4), no drain)
    if (t + 1 < te) stage(t + 1, buf ^ 1);
    // compute current tile
    const char* lb = lds0 + buf * 32768;
#pragma unroll
    for (int sub = 0; sub < 2; sub++) {
      const f32x4 r0v = *(const f32x4*)(lb + rdo[sub][0]);
      const f32x4 r1v = *(const f32x4*)(lb + rdo[sub][1]);
      f16x8 af;
      af[0] = (f16)r0v[0]; af[1] = (f16)r0v[1];
      af[2] = (f16)r0v[2]; af[3] = (f16)r0v[3];
      af[4] = (f16)r1v[0]; af[5] = (f16)r1v[1];
      af[6] = (f16)r1v[2]; af[7] = (f16)r1v[3];
#pragma unroll
      for (int nt = 0; nt < 8; nt++)
        acc[sub][nt] =
            __builtin_amdgcn_mfma_f32_16x16x32_f16(af, Bv[nt], acc[sub][nt], 0, 0, 0);
    }
    // pacing wait: my next-tile stage landed; barrier: everyone's landed and
    // all reads of this buffer are done before it gets overwritten.
    asm volatile("s_waitcnt vmcnt(0)" ::: "memory");
    __builtin_amdgcn_s_barrier();
  }

  // write f32 partials for this K-chunk
  float* Pc = P + ((size_t)c << 21);
#pragma unroll
  for (int sub = 0; sub < 2; sub++) {
    float* prow = Pc + (size_t)(r0 + w * 32 + sub * 16 + kg * 4) * 128 + lr;
#pragma unroll
    for (int nt = 0; nt < 8; nt++)
#pragma unroll
      for (int jr = 0; jr < 4; jr++)
        prow[(size_t)jr * 128 + nt * 16] = acc[sub][nt][jr];
  }
}

// ------------------------------------------------------------- reduce -------
__global__ __launch_bounds__(256) void reduce4(const float* __restrict__ P,
                                               f16* __restrict__ Cn) {
  const int i = blockIdx.x * 256 + threadIdx.x;  // 0..524287
  const size_t o = (size_t)i * 4;
  f32x4 s = *(const f32x4*)(P + o);
  s += *(const f32x4*)(P + (1u << 21) + o);
  s += *(const f32x4*)(P + (2u << 21) + o);
  s += *(const f32x4*)(P + (3u << 21) + o);
  f16x4 h;
  h[0] = (f16)s[0]; h[1] = (f16)s[1]; h[2] = (f16)s[2]; h[3] = (f16)s[3];
  *(f16x4*)(Cn + o) = h;
}

// --------------------------------------------------------------- LSTM -------
// grid: 7 k's x 32 batch-chunks of 16. One wg = 8 waves (512 thr); wave w
// owns hidden units [w*16, w*16+16) across all four gates (4 gate-tiles).
// Wih/Whh fragments in VGPRs (~128), x prefetched 1 step ahead. x-MFMAs run
// before h-MFMAs so the ds_read(h) latency hides under them.
__global__ __launch_bounds__(512, 2) void lstm_run(
    const f16* __restrict__ xh, const f16* __restrict__ t0h,
    const f16* __restrict__ endh, const f16* __restrict__ tauh,
    const f16* __restrict__ nodeh, const f16* __restrict__ coordh,
    const f16* __restrict__ Wih16, const f16* __restrict__ Whh16,
    const float* __restrict__ bsum, const float* __restrict__ hW1,
    const float* __restrict__ hb1, const float* __restrict__ hW2,
    const float* __restrict__ hb2, float* __restrict__ out) {
  __shared__ f16 hbuf[2][16 * NH];  // double-buffered h, XOR-swizzled bytes
  __shared__ float hu[16 * NH];

  const int k = blockIdx.x >> 5;
  const int b0 = (blockIdx.x & 31) << 4;
  const int w = threadIdx.x >> 6;
  const int l = threadIdx.x & 63;
  const int lr = l & 15, kg = l >> 4;

  int len;
  switch (k) {
    case 0: len = 83; break;
    case 1: len = 19; break;
    case 2: len = 32; break;
    case 3: len = 32; break;
    case 4: len = 51; break;
    case 5: len = 64; break;
    default: len = 51; break;
  }

  // per-step input fragment pointer (wave-uniform select logic)
  auto xptr = [&](int t) -> const f16* {
    const f16* cb; int bstr, idx;
    if (k == 2) { cb = nodeh; bstr = 32 * NH; idx = t; }
    else if (k == 3) { cb = coordh; bstr = 32 * NH; idx = t; }
    else if (k == 5) {
      const int q = t >> 2, r = t & 3;
      cb = (r == 0 || r == 2) ? nodeh : coordh;
      bstr = 32 * NH;
      idx = 2 * q + ((r >= 2) ? 1 : 0);
    } else {
      if (t == 0) { cb = xh; bstr = NH; idx = 0; }
      else if (t == 1) { cb = t0h; bstr = NH; idx = 0; }
      else if (t == len - 1) { cb = endh; bstr = NH; idx = 0; }
      else {
        const int u = t - 2;
        if (k == 0) {
          const int q = u / 5, r = u - 5 * q;
          if (r == 0) { cb = tauh; bstr = 16 * NH; idx = q; }
          else if (r == 1) { cb = nodeh; bstr = 32 * NH; idx = 2 * q; }
          else if (r == 2) { cb = coordh; bstr = 32 * NH; idx = 2 * q; }
          else if (r == 3) { cb = nodeh; bstr = 32 * NH; idx = 2 * q + 1; }
          else { cb = coordh; bstr = 32 * NH; idx = 2 * q + 1; }
        } else if (k == 1) { cb = tauh; bstr = 16 * NH; idx = u; }
        else if (k == 4) {
          const int q = u / 3, r = u - 3 * q;
          if (r == 0) { cb = tauh; bstr = 16 * NH; idx = q; }
          else { cb = nodeh; bstr = 32 * NH; idx = 2 * q + (r - 1); }
        } else {  // k == 6
          const int q = u / 3, r = u - 3 * q;
          if (r == 0) { cb = tauh; bstr = 16 * NH; idx = q; }
          else { cb = coordh; bstr = 32 * NH; idx = 2 * q + (r - 1); }
        }
      }
    }
    return cb + (size_t)(b0 + lr) * bstr + idx * NH + kg * 8;
  };

  // ---- load weight fragments into registers ----
  // wave w owns hidden cols [w*16, w*16+16); gate g's row block = g*128.
  f16x8 Wh[4][4], Wi[4][4];
  float bias[4];
  {
    const f16* whb = Whh16 + (size_t)k * 512 * NH;
    const f16* wib = Wih16 + (size_t)k * 512 * NH;
#pragma unroll
    for (int g = 0; g < 4; g++) {
      const int col = g * 128 + w * 16 + lr;
      bias[g] = bsum[k * 512 + col];
#pragma unroll
      for (int kc = 0; kc < 4; kc++) {
        Wh[kc][g] = *(const f16x8*)(whb + (size_t)col * NH + kc * 32 + kg * 8);
        Wi[kc][g] = *(const f16x8*)(wib + (size_t)col * NH + kc * 32 + kg * 8);
      }
    }
  }

  char* lds0 = (char*)&hbuf[0][0];
  // zero h buffer 0 (h0 = 0): 512 threads x 8 B = 4096 B
  *(unsigned long long*)(lds0 + threadIdx.x * 8) = 0ull;
  __syncthreads();

  float c[4] = {0, 0, 0, 0};

  // precomputed swizzled LDS byte offsets (constant across t)
  int rdo[4];
#pragma unroll
  for (int kc = 0; kc < 4; kc++) {
    const int colb = (kc * 32 + kg * 8) * 2;
    rdo[kc] = lr * 256 + (colb ^ ((lr & 7) << 4));
  }
  int wro[4];
#pragma unroll
  for (int jr = 0; jr < 4; jr++) {
    const int hrow = kg * 4 + jr;
    const int hcol = w * 16 + lr;
    wro[jr] = hrow * 256 + ((hcol * 2) ^ ((hrow & 7) << 4));
  }

  // prime x for t=0
  f16x8 axc[4];
  {
    const f16* xp = xptr(0);
#pragma unroll
    for (int kc = 0; kc < 4; kc++) axc[kc] = *(const f16x8*)(xp + kc * 32);
  }

  int cur = 0;
  for (int t = 0; t < len; t++) {
    char* rb = lds0 + cur * 4096;
    f16x8 ah[4];
#pragma unroll
    for (int kc = 0; kc < 4; kc++) ah[kc] = *(const f16x8*)(rb + rdo[kc]);

    // prefetch next-step x into registers (hidden under MFMA+gates+barrier)
    f16x8 axn[4];
    if (t + 1 < len) {
      const f16* xp = xptr(t + 1);
#pragma unroll
      for (int kc = 0; kc < 4; kc++) axn[kc] = *(const f16x8*)(xp + kc * 32);
    }

    f32x4 acc[4];
#pragma unroll
    for (int g = 0; g < 4; g++) {
      f32x4 binit = {bias[g], bias[g], bias[g], bias[g]};
      acc[g] = binit;
    }
    // x-part first (register operands ready) -> hides ds_read(h) latency
#pragma unroll
    for (int kc = 0; kc < 4; kc++)
#pragma unroll
      for (int g = 0; g < 4; g++)
        acc[g] = __builtin_amdgcn_mfma_f32_16x16x32_f16(axc[kc], Wi[kc][g], acc[g], 0, 0, 0);
#pragma unroll
    for (int kc = 0; kc < 4; kc++)
#pragma unroll
      for (int g = 0; g < 4; g++)
        acc[g] = __builtin_amdgcn_mfma_f32_16x16x32_f16(ah[kc], Wh[kc][g], acc[g], 0, 0, 0);

    // gates: acc[0]=i acc[1]=f acc[2]=g acc[3]=o
    char* wb = lds0 + (cur ^ 1) * 4096;
#pragma unroll
    for (int jr = 0; jr < 4; jr++) {
      const float iv = acc[0][jr];
      const float fv = acc[1][jr];
      const float gv = acc[2][jr];
      const float ov = acc[3][jr];
      const float cn = sigf(fv) * c[jr] + sigf(iv) * tanh_fast(gv);
      c[jr] = cn;
      const float hn = sigf(ov) * tanh_fast(cn);
      *(f16*)(wb + wro[jr]) = (f16)hn;
    }
    __syncthreads();
#pragma unroll
    for (int kc = 0; kc < 4; kc++) axc[kc] = axn[kc];
    cur ^= 1;
  }

  // ---- head: out = tanh(h @ W1^T + b1) @ W2^T + b2 ----
  {
    char* rb = lds0 + cur * 4096;
    f16x8 ah[4];
#pragma unroll
    for (int kc = 0; kc < 4; kc++) ah[kc] = *(const f16x8*)(rb + rdo[kc]);
    const float* W1 = hW1 + (size_t)k * NH * NH;
    const int col = w * 16 + lr;
    f32x4 hacc;
    {
      const float b1 = hb1[k * NH + col];
      f32x4 binit = {b1, b1, b1, b1};
      hacc = binit;
    }
#pragma unroll
    for (int kc = 0; kc < 4; kc++) {
      const float* wrow = W1 + (size_t)col * NH + kc * 32 + kg * 8;
      const f32x4 w0 = *(const f32x4*)(wrow);
      const f32x4 w1 = *(const f32x4*)(wrow + 4);
      f16x8 wv;
      wv[0] = (f16)w0[0]; wv[1] = (f16)w0[1]; wv[2] = (f16)w0[2]; wv[3] = (f16)w0[3];
      wv[4] = (f16)w1[0]; wv[5] = (f16)w1[1]; wv[6] = (f16)w1[2]; wv[7] = (f16)w1[3];
      hacc = __builtin_amdgcn_mfma_f32_16x16x32_f16(ah[kc], wv, hacc, 0, 0, 0);
    }
#pragma unroll
    for (int jr = 0; jr < 4; jr++)
      hu[(kg * 4 + jr) * NH + col] = tanh_fast(hacc[jr]);
  }
  __syncthreads();
  if (w == 0) {
    const int b = l >> 2, part = l & 3;
    const float* W2 = hW2 + (size_t)k * NH;
    float s = 0.f;
#pragma unroll
    for (int j = 0; j < 32; j++)
      s += hu[b * NH + part * 32 + j] * W2[part * 32 + j];
    s += __shfl_xor(s, 1);
    s += __shfl_xor(s, 2);
    if (part == 0) out[k * NB + b0 + b] = s + hb2[k];
  }
}

// ------------------------------------------------------------- launch -------
extern "C" void kernel_launch(void* const* d_in, const int* in_sizes, int n_in,
                              void* d_out, int out_size, void* d_ws, size_t ws_size,
                              hipStream_t stream) {
  (void)in_sizes; (void)n_in; (void)out_size; (void)ws_size;
  const float* x = (const float*)d_in[0];
  const float* t0 = (const float*)d_in[1];
  const float* node = (const float*)d_in[2];
  const float* tau = (const float*)d_in[3];
  const float* endi = (const float*)d_in[4];
  const float* coords = (const float*)d_in[5];
  const float* Wx1 = (const float*)d_in[6];
  const float* Wx2 = (const float*)d_in[7];
  const float* bx2 = (const float*)d_in[8];
  const float* Wres = (const float*)d_in[9];
  const float* bres = (const float*)d_in[10];
  const float* Wnode = (const float*)d_in[11];
  const float* Wtau = (const float*)d_in[12];
  const float* btau = (const float*)d_in[13];
  const float* Wend1 = (const float*)d_in[14];
  const float* Wend2 = (const float*)d_in[15];
  const float* bend2 = (const float*)d_in[16];
  const float* Wcoord = (const float*)d_in[17];
  const float* Wih = (const float*)d_in[18];
  const float* Whh = (const float*)d_in[19];
  const float* bih = (const float*)d_in[20];
  const float* bhh = (const float*)d_in[21];
  const float* hW1 = (const float*)d_in[22];
  const float* hb1 = (const float*)d_in[23];
  const float* hW2 = (const float*)d_in[24];
  const float* hb2 = (const float*)d_in[25];

  char* ws = (char*)d_ws;
  f16* xh = (f16*)ws;      ws += (size_t)NB * NH * 2;
  f16* t0h = (f16*)ws;     ws += (size_t)NB * NH * 2;
  f16* endh = (f16*)ws;    ws += (size_t)NB * NH * 2;
  f16* tauh = (f16*)ws;    ws += (size_t)NB * NL * NH * 2;
  f16* nodeh = (f16*)ws;   ws += (size_t)NB * 2 * NL * NH * 2;
  f16* coordh = (f16*)ws;  ws += (size_t)NB * 2 * NL * NH * 2;
  f16* Wf = (f16*)ws;      ws += (size_t)NSTEP * 4096 * 2;
  f16* Wih16 = (f16*)ws;   ws += (size_t)7 * 512 * NH * 2;
  f16* Whh16 = (f16*)ws;   ws += (size_t)7 * 512 * NH * 2;
  float* bsum = (float*)ws; ws += (size_t)7 * 512 * 4;
  float* Pp = (float*)ws;   // 4 x 16384 x 128 f32 partials (33.5 MB)

  prep_kernel<<<1024, 256, 0, stream>>>(
      x, t0, tau, endi, coords, Wx1, Wx2, bx2, Wres, bres, Wnode, Wtau, btau,
      Wend1, Wend2, bend2, Wcoord, Wih, Whh, bih, bhh,
      xh, t0h, endh, tauh, coordh, Wf, Wih16, Whh16, bsum);
  node_gemm<<<256, 512, 0, stream>>>(node, Wf, Pp);
  reduce4<<<2048, 256, 0, stream>>>(Pp, nodeh);
  lstm_run<<<224, 512, 0, stream>>>(xh, t0h, endh, tauh, nodeh, coordh,
                                    Wih16, Whh16, bsum, hW1, hb1, hW2, hb2,
                                    (float*)d_out);
}